// Round 17
// baseline (197.450 us; speedup 1.0000x reference)
//
#include <hip/hip_runtime.h>
#include <math.h>

#define NT     512
#define NWAVES 8
#define GB     4
#define NTOK   20
#define NTT_P  5          // token tiles for 80-row phases

typedef _Float16 f16x8 __attribute__((ext_vector_type(8)));
typedef _Float16 f16x4 __attribute__((ext_vector_type(4)));
typedef _Float16 f16x2 __attribute__((ext_vector_type(2)));
typedef float    f32x4 __attribute__((ext_vector_type(4)));

// Raw phase barrier: LDS-visibility only (proven R15/R16).
#define PHASE_BAR() do {                                      \
    asm volatile("s_waitcnt lgkmcnt(0)" ::: "memory");        \
    __builtin_amdgcn_s_barrier();                             \
    asm volatile("" ::: "memory");                            \
    __builtin_amdgcn_sched_barrier(0);                        \
} while (0)

// ---- ws fp16 section: transposed, zero-padded weights W_T[n][kpad] --------
#define WS_W1A  0        // [160][32]   (N=150,K=13)
#define WS_W1B  5120     // [112][160]  (N=100,K=150)
#define WS_WA0  23040    // [112][128]  wa0 rows 0..99
#define WS_WA1  37376    // [112][128]
#define WS_W2A  51712    // [112][128]
#define WS_W2B  66048    // [64][128]   (N=50,K=100)
#define WS_W3A  74240    // [160][64]   (N=150,K=56)
#define WS_W3B  84480    // [112][160]  (N=100,K=150)
#define WS_W3C  102400   // [112][128]  (N=100,K=100)
#define WS_WA0H 116736   // [112][128]  wa0 rows 100..199 (g part)
#define WS_TOTAL 131072
// ---- ws f32 bias section (zero-padded) ------------------------------------
#define WB_BASE 65536
#define WB_B1A  0
#define WB_B1B  160
#define WB_BA0  272
#define WB_BA1  384
#define WB_B2A  496
#define WB_B2B  608
#define WB_B3A  672
#define WB_B3B  832
#define WB_B3C  944
#define WB_WA2  1056
#define WB_N    1168
#define PREP_TOTAL (WS_TOTAL + WB_N)
// ---- mv staging: fp16 [B][64] ---------------------------------------------
#define WS_MV   135168

// ---- main-kernel LDS arena (halves), 52.9 KB -> 3 blocks/CU ---------------
#define LH_A    0
#define LH_B    12160
#define LH_C    23040
#define LH_T1   LH_A          // stride 152
#define LH_S1   LH_A          // stride 136
#define LH_F1   LH_A          // stride 136
#define LH_H1   LH_B          // stride 136
#define LH_FF   LH_B          // [80][72]
#define LH_GQ   LH_C          // [16][136] strip
#define LF_PART 11520         // f32: part [80][8]
#define LF_GB   12672         // f32: gbias [4][112]
#define LF_ATT  13120         // f32: att [80]
#define LF_SS   13200         // f32: ss [24]
#define LDS_DW  13224
#define LDS_BYTES (LDS_DW * 4)

// ---- tail-kernel LDS arena (halves) ---------------------------------------
#define TB      64
#define TL_MV   0        // [64][72]
#define TL_HA   4608     // [64][168]
#define TL_HB   15360    // [64][136]
#define TL_HC   24064    // [64][136]
#define LDS_T_DW   16384
#define LDS_T_BYTES (LDS_T_DW * 4)

// ---------------------------------------------------------------------------
// prep
// ---------------------------------------------------------------------------
__device__ __forceinline__ void prep_one(const float* __restrict__ src, _Float16* dst,
                                         int local, int N, int K, int Ks)
{
    int n = local / Ks, k = local - n * Ks;
    dst[local] = (_Float16)((n < N && k < K) ? src[k * N + n] : 0.f);
}
__device__ __forceinline__ void prep_b(const float* __restrict__ src, float* dst,
                                       int idx, int N)
{
    dst[idx] = (idx < N) ? src[idx] : 0.f;
}

__global__ __launch_bounds__(256)
void prep_kernel(const float* __restrict__ w1a, const float* __restrict__ w1b,
                 const float* __restrict__ wa0, const float* __restrict__ wa1,
                 const float* __restrict__ w2a, const float* __restrict__ w2b,
                 const float* __restrict__ w3a, const float* __restrict__ w3b,
                 const float* __restrict__ w3c, const float* __restrict__ wa2,
                 const float* __restrict__ b1a, const float* __restrict__ b1b,
                 const float* __restrict__ ba0, const float* __restrict__ ba1,
                 const float* __restrict__ b2a, const float* __restrict__ b2b,
                 const float* __restrict__ b3a, const float* __restrict__ b3b,
                 const float* __restrict__ b3c,
                 _Float16* __restrict__ ws)
{
    int g = blockIdx.x * 256 + threadIdx.x;
    if (g >= PREP_TOTAL) return;
    if (g >= WS_TOTAL) {
        float* wb = (float*)ws + WB_BASE;
        int l = g - WS_TOTAL;
        if (l < WB_B1B)      prep_b(b1a, wb + WB_B1A, l - WB_B1A, 150);
        else if (l < WB_BA0) prep_b(b1b, wb + WB_B1B, l - WB_B1B, 100);
        else if (l < WB_BA1) prep_b(ba0, wb + WB_BA0, l - WB_BA0, 100);
        else if (l < WB_B2A) prep_b(ba1, wb + WB_BA1, l - WB_BA1, 100);
        else if (l < WB_B2B) prep_b(b2a, wb + WB_B2A, l - WB_B2A, 100);
        else if (l < WB_B3A) prep_b(b2b, wb + WB_B2B, l - WB_B2B, 50);
        else if (l < WB_B3B) prep_b(b3a, wb + WB_B3A, l - WB_B3A, 150);
        else if (l < WB_B3C) prep_b(b3b, wb + WB_B3B, l - WB_B3B, 100);
        else if (l < WB_WA2) prep_b(b3c, wb + WB_B3C, l - WB_B3C, 100);
        else                 prep_b(wa2, wb + WB_WA2, l - WB_WA2, 100);
        return;
    }
    if (g < WS_W1B)       prep_one(w1a, ws + WS_W1A, g - WS_W1A, 150, 13, 32);
    else if (g < WS_WA0)  prep_one(w1b, ws + WS_W1B, g - WS_W1B, 100, 150, 160);
    else if (g < WS_WA1)  prep_one(wa0, ws + WS_WA0, g - WS_WA0, 100, 100, 128);
    else if (g < WS_W2A)  prep_one(wa1, ws + WS_WA1, g - WS_WA1, 100, 100, 128);
    else if (g < WS_W2B)  prep_one(w2a, ws + WS_W2A, g - WS_W2A, 100, 100, 128);
    else if (g < WS_W3A)  prep_one(w2b, ws + WS_W2B, g - WS_W2B,  50, 100, 128);
    else if (g < WS_W3B)  prep_one(w3a, ws + WS_W3A, g - WS_W3A, 150,  56, 64);
    else if (g < WS_W3C)  prep_one(w3b, ws + WS_W3B, g - WS_W3B, 100, 150, 160);
    else if (g < WS_WA0H) prep_one(w3c, ws + WS_W3C, g - WS_W3C, 100, 100, 128);
    else                  prep_one(wa0 + 100 * 100, ws + WS_WA0H, g - WS_WA0H, 100, 100, 128);
}

// ---------------------------------------------------------------------------
// Monolithic swapped-operand GEMM (R12-proven): item = mt, W loaded in-phase.
// ---------------------------------------------------------------------------
template<int KT, int MTL, int NTT, bool RELU, int BMODE, int OMODE, int CLW, int NW>
__device__ __forceinline__ void gemm_sw(const _Float16* X, const int Xs,
                                        const _Float16* __restrict__ WT, const int Bs,
                                        const float* __restrict__ biasp,
                                        const float* gbias,
                                        _Float16* Y, const int Ys,
                                        float* part, const float* __restrict__ wa2p,
                                        const int wv, const int lane)
{
    const int cl = lane & 15, kq = lane >> 4;
    constexpr int IPW = (MTL + NW - 1) / NW;
    f16x8 wf[IPW][KT];
    f32x4 bv[IPW];
#pragma unroll
    for (int ii = 0; ii < IPW; ++ii) {
        const int mt = wv + ii * NW;
        if (mt < MTL) {
            const _Float16* Wp = WT + (mt * 16 + cl) * Bs + kq * 8;
#pragma unroll
            for (int kt = 0; kt < KT; ++kt) wf[ii][kt] = *(const f16x8*)(Wp + kt * 32);
            if (BMODE == 0)
                bv[ii] = *(const f32x4*)(biasp + mt * 16 + kq * 4);
        }
    }
#pragma unroll
    for (int ii = 0; ii < IPW; ++ii) {
        const int mt = wv + ii * NW;
        if (mt >= MTL) break;
        const int fb = mt * 16 + kq * 4;
#pragma unroll
        for (int nt = 0; nt < NTT; ++nt) {
            const _Float16* Xp = X + (nt * 16 + cl) * Xs + kq * 8;
            f16x8 xf[KT];
#pragma unroll
            for (int kt = 0; kt < KT; ++kt) xf[kt] = *(const f16x8*)(Xp + kt * 32);
            f32x4 acc = {0.f, 0.f, 0.f, 0.f};
#pragma unroll
            for (int kt = 0; kt < KT; ++kt)
                acc = __builtin_amdgcn_mfma_f32_16x16x32_f16(wf[ii][kt], xf[kt], acc, 0, 0, 0);
            const int token = nt * 16 + cl;
            if (OMODE == 1) {
                if (cl < GB) {
                    f32x4 o = acc + bv[ii];
                    *(f32x4*)((float*)Y + cl * 112 + fb) = o;
                }
            } else if (OMODE == 2) {
                f32x4 y = acc + bv[ii];
                y[0] = fmaxf(y[0], 0.f); y[1] = fmaxf(y[1], 0.f);
                y[2] = fmaxf(y[2], 0.f); y[3] = fmaxf(y[3], 0.f);
                f32x4 w4 = *(const f32x4*)(wa2p + fb);
                float p = y[0] * w4[0] + y[1] * w4[1] + y[2] * w4[2] + y[3] * w4[3];
                p += __shfl_xor(p, 16);
                p += __shfl_xor(p, 32);
                if (kq == 0) part[token * 8 + mt] = p;
            } else {
                f32x4 bb;
                if (BMODE == 1)
                    bb = *(const f32x4*)(gbias + (token / NTOK) * 112 + fb);
                else
                    bb = bv[ii];
                f32x4 y = acc + bb;
                if (RELU) {
                    y[0] = fmaxf(y[0], 0.f); y[1] = fmaxf(y[1], 0.f);
                    y[2] = fmaxf(y[2], 0.f); y[3] = fmaxf(y[3], 0.f);
                }
                if (fb < CLW) {
                    f16x4 o = { (_Float16)y[0], (_Float16)y[1],
                                (_Float16)y[2], (_Float16)y[3] };
                    *(f16x4*)(Y + token * Ys + fb) = o;
                }
            }
        }
    }
}

// ---------------------------------------------------------------------------
// Paired-mt GEMM: wave wv -> pair p=wv>>1 owns mts {2p,2p+1} (pair 3 = {6}),
// h=wv&1 owns nts {0,1,2} or {3,4}. X read ONCE per (nt,kt), shared by both
// mts -> X LDS traffic halved vs gemm_sw. Static mapping, no item loops.
// ---------------------------------------------------------------------------
template<bool RELU, int BMODE, int OMODE>
__device__ __forceinline__ void pair_epi(f32x4 acc, f32x4 bvv, int mt, int token,
                                         int kq, const float* gbias,
                                         _Float16* Y, int Ys, float* part,
                                         const float* __restrict__ wa2p)
{
    const int fb = mt * 16 + kq * 4;
    if (OMODE == 2) {
        f32x4 y = acc + bvv;
        y[0] = fmaxf(y[0], 0.f); y[1] = fmaxf(y[1], 0.f);
        y[2] = fmaxf(y[2], 0.f); y[3] = fmaxf(y[3], 0.f);
        f32x4 w4 = *(const f32x4*)(wa2p + fb);
        float p = y[0] * w4[0] + y[1] * w4[1] + y[2] * w4[2] + y[3] * w4[3];
        p += __shfl_xor(p, 16);
        p += __shfl_xor(p, 32);
        if (kq == 0) part[token * 8 + mt] = p;
    } else {
        f32x4 bb = (BMODE == 1)
            ? *(const f32x4*)(gbias + (token / NTOK) * 112 + fb) : bvv;
        f32x4 y = acc + bb;
        if (RELU) {
            y[0] = fmaxf(y[0], 0.f); y[1] = fmaxf(y[1], 0.f);
            y[2] = fmaxf(y[2], 0.f); y[3] = fmaxf(y[3], 0.f);
        }
        f16x4 o = { (_Float16)y[0], (_Float16)y[1],
                    (_Float16)y[2], (_Float16)y[3] };
        *(f16x4*)(Y + token * Ys + fb) = o;
    }
}

template<int KT, int MTL, bool RELU, int BMODE, int OMODE>
__device__ __forceinline__ void gemm_pair(const _Float16* X, const int Xs,
                                          const _Float16* __restrict__ WT, const int Bs,
                                          const float* __restrict__ biasp,
                                          const float* gbias,
                                          _Float16* Y, const int Ys,
                                          float* part, const float* __restrict__ wa2p,
                                          const int wv, const int lane)
{
    const int cl = lane & 15, kq = lane >> 4;
    const int p = wv >> 1, h = wv & 1;
    const int mt0 = 2 * p, mt1 = 2 * p + 1;
    const bool two = (mt1 < MTL);
    f16x8 w0[KT], w1[KT];
    f32x4 b0 = {0.f, 0.f, 0.f, 0.f}, b1 = {0.f, 0.f, 0.f, 0.f};
    {
        const _Float16* Wp0 = WT + (mt0 * 16 + cl) * Bs + kq * 8;
#pragma unroll
        for (int kt = 0; kt < KT; ++kt) w0[kt] = *(const f16x8*)(Wp0 + kt * 32);
        if (BMODE == 0) b0 = *(const f32x4*)(biasp + mt0 * 16 + kq * 4);
        if (two) {
            const _Float16* Wp1 = WT + (mt1 * 16 + cl) * Bs + kq * 8;
#pragma unroll
            for (int kt = 0; kt < KT; ++kt) w1[kt] = *(const f16x8*)(Wp1 + kt * 32);
            if (BMODE == 0) b1 = *(const f32x4*)(biasp + mt1 * 16 + kq * 4);
        }
    }
#pragma unroll
    for (int i = 0; i < 3; ++i) {
        if (h && i == 2) break;          // h=1 waves own only nts {3,4}
        const int nt = h ? (3 + i) : i;
        const _Float16* Xp = X + (nt * 16 + cl) * Xs + kq * 8;
        f16x8 xf[KT];
#pragma unroll
        for (int kt = 0; kt < KT; ++kt) xf[kt] = *(const f16x8*)(Xp + kt * 32);
        f32x4 a0 = {0.f, 0.f, 0.f, 0.f}, a1 = {0.f, 0.f, 0.f, 0.f};
#pragma unroll
        for (int kt = 0; kt < KT; ++kt) {
            a0 = __builtin_amdgcn_mfma_f32_16x16x32_f16(w0[kt], xf[kt], a0, 0, 0, 0);
            if (two)
                a1 = __builtin_amdgcn_mfma_f32_16x16x32_f16(w1[kt], xf[kt], a1, 0, 0, 0);
        }
        const int token = nt * 16 + cl;
        pair_epi<RELU, BMODE, OMODE>(a0, b0, mt0, token, kq, gbias, Y, Ys, part, wa2p);
        if (two)
            pair_epi<RELU, BMODE, OMODE>(a1, b1, mt1, token, kq, gbias, Y, Ys, part, wa2p);
    }
}

// ===========================================================================
// MAIN kernel: paired-mt heavy phases, raw lgkm barriers, no W-prefetch.
// ===========================================================================
__global__ __launch_bounds__(NT, 6)
void vnet_kernel(const float* __restrict__ x,
                 const float* __restrict__ ba2,
                 const _Float16* __restrict__ wsh,
                 _Float16* __restrict__ mvg)
{
    extern __shared__ float lds_f[];
    _Float16* lds_h = (_Float16*)lds_f;

    const int tid  = threadIdx.x;
    const int lane = tid & 63, wv = tid >> 6;
    const int b0   = blockIdx.x * GB;
    const float* wb = (const float*)wsh + WB_BASE;

    _Float16* xa  = lds_h + LH_C;
    _Float16* gqh = lds_h + LH_GQ;
    _Float16* h1w = lds_h + LH_H1;
    float* gbias = lds_f + LF_GB;
    float* att   = lds_f + LF_ATT;
    float* ss    = lds_f + LF_SS;
    float* part  = lds_f + LF_PART;

    // ---- P1: x -> C [token][40]; targeted pad zeroing --------------------
    const float* xg = x + (size_t)b0 * (NTOK * 13);
    for (int t = tid; t < GB * NTOK * 13; t += NT) {
        int row = t / 13, d = t - row * 13;
        xa[row * 40 + d] = (_Float16)xg[t];
    }
    for (int t = tid; t < 80 * 27; t += NT) {
        int row = t / 27, c = 13 + (t - row * 27);
        xa[row * 40 + c] = (_Float16)0.f;
    }
    for (int t = tid; t < 80 * 24; t += NT) {
        int row = t / 24, c = 112 + (t - row * 24);
        h1w[row * 136 + c] = (_Float16)0.f;
    }
    if (tid < 8) h1w[tid] = (_Float16)0.f;
    if (tid < GB * 6) {
        int b = tid / 6, d = tid - b * 6;
        ss[tid] = xg[b * (NTOK * 13) + d];   // x[b,0,d]
    }
    PHASE_BAR();

    // ---- P2: t1 = relu(x @ w1a + b1a) -> A [80][152] ---------------------
    gemm_sw<1, 10, NTT_P, true, 0, 0, 152, 8>(xa, 40, wsh + WS_W1A, 32,
        wb + WB_B1A, nullptr, lds_h + LH_T1, 152, nullptr, nullptr, wv, lane);
    PHASE_BAR();

    // ---- P3: h1 = relu(t1 @ w1b + b1b) -> B [80][136] --------------------
    gemm_sw<5, 7, NTT_P, true, 0, 0, 10000, 8>(lds_h + LH_T1, 152, wsh + WS_W1B,
        160, wb + WB_B1B, nullptr, h1w, 136, nullptr, nullptr, wv, lane);
    PHASE_BAR();

    // ---- P4: gq strip (u32-paired reads) ---------------------------------
    const _Float16* h1 = h1w;
    const uint* h1u = (const uint*)h1;
    for (int t = tid; t < GB * 50; t += NT) {
        int b = t / 50, cp = t - b * 50;
        float s0 = 0.f, s1 = 0.f;
#pragma unroll
        for (int n = 0; n < NTOK; ++n) {
            uint v = h1u[(b * NTOK + n) * 68 + cp];
            f16x2 pq = *(const f16x2*)&v;
            s0 += (float)pq.x; s1 += (float)pq.y;
        }
        f16x2 g = { (_Float16)(s0 * 0.05f), (_Float16)(s1 * 0.05f) };
        *(f16x2*)(gqh + b * 136 + 2 * cp) = g;
    }
    PHASE_BAR();

    // ---- Mg: gbias = ba0 + gq @ wa0_hi (f32 out) -------------------------
    gemm_sw<4, 7, 1, false, 0, 1, 10000, 8>(gqh, 136, wsh + WS_WA0H, 128,
        wb + WB_BA0, nullptr, (_Float16*)gbias, 0, nullptr, nullptr, wv, lane);
    PHASE_BAR();

    // ---- M1: s1 = relu(h1 @ wa0_lo + gbias) -> A (paired) ----------------
    gemm_pair<4, 7, true, 1, 0>(h1, 136, wsh + WS_WA0, 128, nullptr, gbias,
        lds_h + LH_S1, 136, nullptr, nullptr, wv, lane);
    PHASE_BAR();

    // ---- M2: s2-scores partials from s1 (paired, no s2 store) ------------
    gemm_pair<4, 7, true, 0, 2>(lds_h + LH_S1, 136, wsh + WS_WA1, 128,
        wb + WB_BA1, nullptr, nullptr, 0, part, wb + WB_WA2, wv, lane);
    PHASE_BAR();

    // ---- M3: f1 = relu(h1 @ w2a + b2a) -> A (paired) ---------------------
    gemm_pair<4, 7, true, 0, 0>(h1, 136, wsh + WS_W2A, 128, wb + WB_B2A,
        nullptr, lds_h + LH_F1, 136, nullptr, nullptr, wv, lane);
    PHASE_BAR();

    // ---- M4: f = f1 @ w2b + b2b -> B head (waves 0-3); softmax (4-7) -----
    if (wv < 4) {
        gemm_sw<4, 4, NTT_P, false, 0, 0, 10000, 4>(lds_h + LH_F1, 136,
            wsh + WS_W2B, 128, wb + WB_B2B, nullptr, lds_h + LH_FF, 72,
            nullptr, nullptr, wv, lane);
    } else {
        const int b = wv - 4;
        float sc = -1e30f;
        if (lane < NTOK) {
            sc = ba2[0];
            const float* pr = part + (b * NTOK + lane) * 8;
#pragma unroll
            for (int m = 0; m < 7; ++m) sc += pr[m];
        }
        float mx = sc;
#pragma unroll
        for (int off = 16; off; off >>= 1) mx = fmaxf(mx, __shfl_xor(mx, off, 32));
        float e = (lane < NTOK) ? expf(sc - mx) : 0.f;
        float s = e;
#pragma unroll
        for (int off = 16; off; off >>= 1) s += __shfl_xor(s, off, 32);
        if (lane < NTOK) att[b * NTOK + lane] = e / s;
    }
    PHASE_BAR();

    // ---- P10: mv[b][c] = [ss | wf | 0-pad] -> GLOBAL fp16 [B][64] --------
    const _Float16* fh = lds_h + LH_FF;
    for (int t = tid; t < GB * 64; t += NT) {
        int b = t >> 6, c = t & 63;
        float v = 0.f;
        if (c < 6) {
            v = ss[b * 6 + c];
        } else if (c < 56) {
            const int cc = c - 6;
            const float* ab = att + b * NTOK;
            float acc = 0.f;
#pragma unroll
            for (int n = 0; n < NTOK; ++n)
                acc = fmaf((float)fh[(b * NTOK + n) * 72 + cc], ab[n], acc);
            v = acc;
        }
        mvg[(size_t)(b0 + b) * 64 + c] = (_Float16)v;
    }
}

// ===========================================================================
// TAIL kernel (unchanged from R16): 64 batches/block, W-prefetch ping.
// ===========================================================================
template<int KT, int MTL, int NW>
struct WC {
    static constexpr int IPW = (MTL + NW - 1) / NW;
    f16x8 wf[IPW][KT];
    f32x4 bv[IPW];
};

template<int KT, int MTL, int NW, bool LOADB>
__device__ __forceinline__ void load_w(WC<KT, MTL, NW>& W,
                                       const _Float16* __restrict__ WT, const int Bs,
                                       const float* __restrict__ biasp,
                                       const int wv, const int lane)
{
    const int cl = lane & 15, kq = lane >> 4;
#pragma unroll
    for (int ii = 0; ii < WC<KT, MTL, NW>::IPW; ++ii) {
        const int mt = wv + ii * NW;
        if (mt < MTL) {
            const _Float16* Wp = WT + (mt * 16 + cl) * Bs + kq * 8;
#pragma unroll
            for (int kt = 0; kt < KT; ++kt) W.wf[ii][kt] = *(const f16x8*)(Wp + kt * 32);
            if (LOADB) W.bv[ii] = *(const f32x4*)(biasp + mt * 16 + kq * 4);
        }
    }
}

template<int KT, int MTL, int NTT, bool RELU, int NW>
__device__ __forceinline__ void gemm_wc(const WC<KT, MTL, NW>& W,
                                        const _Float16* X, const int Xs,
                                        _Float16* Y, const int Ys,
                                        const int wv, const int lane)
{
    const int cl = lane & 15, kq = lane >> 4;
#pragma unroll
    for (int ii = 0; ii < WC<KT, MTL, NW>::IPW; ++ii) {
        const int mt = wv + ii * NW;
        if (mt >= MTL) break;
        const int fb = mt * 16 + kq * 4;
#pragma unroll
        for (int nt = 0; nt < NTT; ++nt) {
            const _Float16* Xp = X + (nt * 16 + cl) * Xs + kq * 8;
            f16x8 xf[KT];
#pragma unroll
            for (int kt = 0; kt < KT; ++kt) xf[kt] = *(const f16x8*)(Xp + kt * 32);
            f32x4 acc = {0.f, 0.f, 0.f, 0.f};
#pragma unroll
            for (int kt = 0; kt < KT; ++kt)
                acc = __builtin_amdgcn_mfma_f32_16x16x32_f16(W.wf[ii][kt], xf[kt], acc, 0, 0, 0);
            const int token = nt * 16 + cl;
            f32x4 y = acc + W.bv[ii];
            if (RELU) {
                y[0] = fmaxf(y[0], 0.f); y[1] = fmaxf(y[1], 0.f);
                y[2] = fmaxf(y[2], 0.f); y[3] = fmaxf(y[3], 0.f);
            }
            f16x4 o = { (_Float16)y[0], (_Float16)y[1],
                        (_Float16)y[2], (_Float16)y[3] };
            *(f16x4*)(Y + token * Ys + fb) = o;
        }
    }
}

__global__ __launch_bounds__(NT)
void tail_kernel(const _Float16* __restrict__ mvg,
                 const float* __restrict__ w3d, const float* __restrict__ b3d,
                 const _Float16* __restrict__ wsh,
                 float* __restrict__ outp)
{
    extern __shared__ float lds_f[];
    _Float16* lds_h = (_Float16*)lds_f;

    const int tid  = threadIdx.x;
    const int lane = tid & 63, wv = tid >> 6;
    const int g0   = blockIdx.x * TB;
    const float* wb = (const float*)wsh + WB_BASE;

    WC<2, 10, 8> Wt1; WC<5, 7, 8> Wt2; WC<4, 7, 8> Wt3;
    load_w<2, 10, 8, true>(Wt1, wsh + WS_W3A, 64, wb + WB_B3A, wv, lane);

    // ---- L: load mv -> LDS stride 72 -------------------------------------
    _Float16* mvT = lds_h + TL_MV;
    {
        const uint* src = (const uint*)(mvg + (size_t)g0 * 64);
        uint* dst = (uint*)mvT;
        for (int t = tid; t < TB * 32; t += NT) {
            int row = t >> 5, c = t & 31;
            dst[row * 36 + c] = src[t];
        }
    }
    for (int t = tid; t < (TL_HC - TL_HB) / 2; t += NT)
        ((uint*)(lds_h + TL_HB))[t] = 0u;
    __syncthreads();

    // ---- T1: ha = relu(mv @ w3a + b3a)  [64][168], K=64 ------------------
    load_w<5, 7, 8, true>(Wt2, wsh + WS_W3B, 160, wb + WB_B3B, wv, lane);
    gemm_wc<2, 10, 4, true, 8>(Wt1, mvT, 72, lds_h + TL_HA, 168, wv, lane);
    __syncthreads();

    // ---- T2: hb = relu(ha @ w3b + b3b)  [64][136], K=160 -----------------
    load_w<4, 7, 8, true>(Wt3, wsh + WS_W3C, 128, wb + WB_B3C, wv, lane);
    gemm_wc<5, 7, 4, true, 8>(Wt2, lds_h + TL_HA, 168, lds_h + TL_HB, 136, wv, lane);
    __syncthreads();

    // ---- T3: hc = relu(hb @ w3c + b3c)  [64][136], K=128 -----------------
    gemm_wc<4, 7, 4, true, 8>(Wt3, lds_h + TL_HB, 136, lds_h + TL_HC, 136, wv, lane);
    __syncthreads();

    // ---- T4: out = hc . w3d + b3d  (8 lanes per batch) -------------------
    {
        const int b = tid >> 3, kl = tid & 7;
        const _Float16* hc = lds_h + TL_HC + b * 136;
        float acc = 0.f;
#pragma unroll 13
        for (int k = kl; k < 100; k += 8)
            acc = fmaf((float)hc[k], w3d[k], acc);
        acc += __shfl_xor(acc, 1);
        acc += __shfl_xor(acc, 2);
        acc += __shfl_xor(acc, 4);
        if (kl == 0) outp[g0 + b] = acc + b3d[0];
    }
}

extern "C" void kernel_launch(void* const* d_in, const int* in_sizes, int n_in,
                              void* d_out, int out_size, void* d_ws, size_t ws_size,
                              hipStream_t stream)
{
    const float* x   = (const float*)d_in[0];
    const float* w1a = (const float*)d_in[1];
    const float* b1a = (const float*)d_in[2];
    const float* w1b = (const float*)d_in[3];
    const float* b1b = (const float*)d_in[4];
    const float* wa0 = (const float*)d_in[5];
    const float* ba0 = (const float*)d_in[6];
    const float* wa1 = (const float*)d_in[7];
    const float* ba1 = (const float*)d_in[8];
    const float* wa2 = (const float*)d_in[9];
    const float* ba2 = (const float*)d_in[10];
    const float* w2a = (const float*)d_in[11];
    const float* b2a = (const float*)d_in[12];
    const float* w2b = (const float*)d_in[13];
    const float* b2b = (const float*)d_in[14];
    const float* w3a = (const float*)d_in[15];
    const float* b3a = (const float*)d_in[16];
    const float* w3b = (const float*)d_in[17];
    const float* b3b = (const float*)d_in[18];
    const float* w3c = (const float*)d_in[19];
    const float* b3c = (const float*)d_in[20];
    const float* w3d = (const float*)d_in[21];
    const float* b3d = (const float*)d_in[22];
    float* outp = (float*)d_out;
    _Float16* wsh = (_Float16*)d_ws;
    _Float16* mvg = wsh + WS_MV;

    hipFuncSetAttribute((const void*)vnet_kernel,
                        hipFuncAttributeMaxDynamicSharedMemorySize, LDS_BYTES);
    hipFuncSetAttribute((const void*)tail_kernel,
                        hipFuncAttributeMaxDynamicSharedMemorySize, LDS_T_BYTES);

    hipLaunchKernelGGL(prep_kernel, dim3((PREP_TOTAL + 255) / 256), dim3(256),
                       0, stream,
                       w1a, w1b, wa0, wa1, w2a, w2b, w3a, w3b, w3c, wa2,
                       b1a, b1b, ba0, ba1, b2a, b2b, b3a, b3b, b3c, wsh);

    const int B = 16384;
    hipLaunchKernelGGL(vnet_kernel, dim3(B / GB), dim3(NT), LDS_BYTES, stream,
                       x, ba2, wsh, mvg);
    hipLaunchKernelGGL(tail_kernel, dim3(B / TB), dim3(NT), LDS_T_BYTES, stream,
                       mvg, w3d, b3d, wsh, outp);
}

// Round 18
// 187.827 us; speedup vs baseline: 1.0512x; 1.0512x over previous
//
#include <hip/hip_runtime.h>
#include <math.h>

#define NT     512
#define NWAVES 8
#define GB     4
#define NTOK   20
#define NTT_P  5          // token tiles for 80-row phases

typedef _Float16 f16x8 __attribute__((ext_vector_type(8)));
typedef _Float16 f16x4 __attribute__((ext_vector_type(4)));
typedef _Float16 f16x2 __attribute__((ext_vector_type(2)));
typedef float    f32x4 __attribute__((ext_vector_type(4)));

// Raw phase barrier: LDS-visibility only (proven R15/R16).
#define PHASE_BAR() do {                                      \
    asm volatile("s_waitcnt lgkmcnt(0)" ::: "memory");        \
    __builtin_amdgcn_s_barrier();                             \
    asm volatile("" ::: "memory");                            \
    __builtin_amdgcn_sched_barrier(0);                        \
} while (0)

// ---- ws fp16 section: transposed, zero-padded weights W_T[n][kpad] --------
#define WS_W1A  0        // [160][32]   (N=150,K=13)
#define WS_W1B  5120     // [112][160]  (N=100,K=150)
#define WS_WA0  23040    // [112][128]  wa0 rows 0..99
#define WS_WA1  37376    // [112][128]
#define WS_W2A  51712    // [112][128]
#define WS_W2B  66048    // [64][128]   (N=50,K=100)
#define WS_W3A  74240    // [160][64]   (N=150,K=56)
#define WS_W3B  84480    // [112][160]  (N=100,K=150)
#define WS_W3C  102400   // [112][128]  (N=100,K=100)
#define WS_WA0H 116736   // [112][128]  wa0 rows 100..199 (g part)
#define WS_TOTAL 131072
// ---- ws f32 bias section (zero-padded) ------------------------------------
#define WB_BASE 65536
#define WB_B1A  0
#define WB_B1B  160
#define WB_BA0  272
#define WB_BA1  384
#define WB_B2A  496
#define WB_B2B  608
#define WB_B3A  672
#define WB_B3B  832
#define WB_B3C  944
#define WB_WA2  1056
#define WB_N    1168
#define PREP_TOTAL (WS_TOTAL + WB_N)
// ---- mv staging: fp16 [B][64] ---------------------------------------------
#define WS_MV   135168

// ---- main-kernel LDS arena (halves), 52.9 KB -> 3 blocks/CU ---------------
#define LH_A    0
#define LH_B    12160
#define LH_C    23040
#define LH_T1   LH_A          // stride 152
#define LH_S1   LH_A          // stride 136
#define LH_F1   LH_A          // stride 136
#define LH_H1   LH_B          // stride 136
#define LH_FF   LH_B          // [80][72]
#define LH_GQ   LH_C          // [16][136] strip
#define LF_PART 11520         // f32: part [80][8]
#define LF_GB   12672         // f32: gbias [4][112]
#define LF_ATT  13120         // f32: att [80]
#define LF_SS   13200         // f32: ss [24]
#define LDS_DW  13224
#define LDS_BYTES (LDS_DW * 4)

// ---- tail-kernel LDS arena (halves) ---------------------------------------
#define TB      64
#define TL_MV   0        // [64][72]
#define TL_HA   4608     // [64][168]
#define TL_HB   15360    // [64][136]
#define TL_HC   24064    // [64][136]
#define LDS_T_DW   16384
#define LDS_T_BYTES (LDS_T_DW * 4)

// ---------------------------------------------------------------------------
// prep
// ---------------------------------------------------------------------------
__device__ __forceinline__ void prep_one(const float* __restrict__ src, _Float16* dst,
                                         int local, int N, int K, int Ks)
{
    int n = local / Ks, k = local - n * Ks;
    dst[local] = (_Float16)((n < N && k < K) ? src[k * N + n] : 0.f);
}
__device__ __forceinline__ void prep_b(const float* __restrict__ src, float* dst,
                                       int idx, int N)
{
    dst[idx] = (idx < N) ? src[idx] : 0.f;
}

__global__ __launch_bounds__(256)
void prep_kernel(const float* __restrict__ w1a, const float* __restrict__ w1b,
                 const float* __restrict__ wa0, const float* __restrict__ wa1,
                 const float* __restrict__ w2a, const float* __restrict__ w2b,
                 const float* __restrict__ w3a, const float* __restrict__ w3b,
                 const float* __restrict__ w3c, const float* __restrict__ wa2,
                 const float* __restrict__ b1a, const float* __restrict__ b1b,
                 const float* __restrict__ ba0, const float* __restrict__ ba1,
                 const float* __restrict__ b2a, const float* __restrict__ b2b,
                 const float* __restrict__ b3a, const float* __restrict__ b3b,
                 const float* __restrict__ b3c,
                 _Float16* __restrict__ ws)
{
    int g = blockIdx.x * 256 + threadIdx.x;
    if (g >= PREP_TOTAL) return;
    if (g >= WS_TOTAL) {
        float* wb = (float*)ws + WB_BASE;
        int l = g - WS_TOTAL;
        if (l < WB_B1B)      prep_b(b1a, wb + WB_B1A, l - WB_B1A, 150);
        else if (l < WB_BA0) prep_b(b1b, wb + WB_B1B, l - WB_B1B, 100);
        else if (l < WB_BA1) prep_b(ba0, wb + WB_BA0, l - WB_BA0, 100);
        else if (l < WB_B2A) prep_b(ba1, wb + WB_BA1, l - WB_BA1, 100);
        else if (l < WB_B2B) prep_b(b2a, wb + WB_B2A, l - WB_B2A, 100);
        else if (l < WB_B3A) prep_b(b2b, wb + WB_B2B, l - WB_B2B, 50);
        else if (l < WB_B3B) prep_b(b3a, wb + WB_B3A, l - WB_B3A, 150);
        else if (l < WB_B3C) prep_b(b3b, wb + WB_B3B, l - WB_B3B, 100);
        else if (l < WB_WA2) prep_b(b3c, wb + WB_B3C, l - WB_B3C, 100);
        else                 prep_b(wa2, wb + WB_WA2, l - WB_WA2, 100);
        return;
    }
    if (g < WS_W1B)       prep_one(w1a, ws + WS_W1A, g - WS_W1A, 150, 13, 32);
    else if (g < WS_WA0)  prep_one(w1b, ws + WS_W1B, g - WS_W1B, 100, 150, 160);
    else if (g < WS_WA1)  prep_one(wa0, ws + WS_WA0, g - WS_WA0, 100, 100, 128);
    else if (g < WS_W2A)  prep_one(wa1, ws + WS_WA1, g - WS_WA1, 100, 100, 128);
    else if (g < WS_W2B)  prep_one(w2a, ws + WS_W2A, g - WS_W2A, 100, 100, 128);
    else if (g < WS_W3A)  prep_one(w2b, ws + WS_W2B, g - WS_W2B,  50, 100, 128);
    else if (g < WS_W3B)  prep_one(w3a, ws + WS_W3A, g - WS_W3A, 150,  56, 64);
    else if (g < WS_W3C)  prep_one(w3b, ws + WS_W3B, g - WS_W3B, 100, 150, 160);
    else if (g < WS_WA0H) prep_one(w3c, ws + WS_W3C, g - WS_W3C, 100, 100, 128);
    else                  prep_one(wa0 + 100 * 100, ws + WS_WA0H, g - WS_WA0H, 100, 100, 128);
}

// ---------------------------------------------------------------------------
// Monolithic swapped-operand GEMM (R12-proven): item = mt, W loaded in-phase.
// ---------------------------------------------------------------------------
template<int KT, int MTL, int NTT, bool RELU, int BMODE, int OMODE, int CLW, int NW>
__device__ __forceinline__ void gemm_sw(const _Float16* X, const int Xs,
                                        const _Float16* __restrict__ WT, const int Bs,
                                        const float* __restrict__ biasp,
                                        const float* gbias,
                                        _Float16* Y, const int Ys,
                                        float* part, const float* __restrict__ wa2p,
                                        const int wv, const int lane)
{
    const int cl = lane & 15, kq = lane >> 4;
    constexpr int IPW = (MTL + NW - 1) / NW;
    f16x8 wf[IPW][KT];
    f32x4 bv[IPW];
#pragma unroll
    for (int ii = 0; ii < IPW; ++ii) {
        const int mt = wv + ii * NW;
        if (mt < MTL) {
            const _Float16* Wp = WT + (mt * 16 + cl) * Bs + kq * 8;
#pragma unroll
            for (int kt = 0; kt < KT; ++kt) wf[ii][kt] = *(const f16x8*)(Wp + kt * 32);
            if (BMODE == 0)
                bv[ii] = *(const f32x4*)(biasp + mt * 16 + kq * 4);
        }
    }
#pragma unroll
    for (int ii = 0; ii < IPW; ++ii) {
        const int mt = wv + ii * NW;
        if (mt >= MTL) break;
        const int fb = mt * 16 + kq * 4;
#pragma unroll
        for (int nt = 0; nt < NTT; ++nt) {
            const _Float16* Xp = X + (nt * 16 + cl) * Xs + kq * 8;
            f16x8 xf[KT];
#pragma unroll
            for (int kt = 0; kt < KT; ++kt) xf[kt] = *(const f16x8*)(Xp + kt * 32);
            f32x4 acc = {0.f, 0.f, 0.f, 0.f};
#pragma unroll
            for (int kt = 0; kt < KT; ++kt)
                acc = __builtin_amdgcn_mfma_f32_16x16x32_f16(wf[ii][kt], xf[kt], acc, 0, 0, 0);
            const int token = nt * 16 + cl;
            if (OMODE == 1) {
                if (cl < GB) {
                    f32x4 o = acc + bv[ii];
                    *(f32x4*)((float*)Y + cl * 112 + fb) = o;
                }
            } else if (OMODE == 2) {
                f32x4 y = acc + bv[ii];
                y[0] = fmaxf(y[0], 0.f); y[1] = fmaxf(y[1], 0.f);
                y[2] = fmaxf(y[2], 0.f); y[3] = fmaxf(y[3], 0.f);
                f32x4 w4 = *(const f32x4*)(wa2p + fb);
                float p = y[0] * w4[0] + y[1] * w4[1] + y[2] * w4[2] + y[3] * w4[3];
                p += __shfl_xor(p, 16);
                p += __shfl_xor(p, 32);
                if (kq == 0) part[token * 8 + mt] = p;
            } else {
                f32x4 bb;
                if (BMODE == 1)
                    bb = *(const f32x4*)(gbias + (token / NTOK) * 112 + fb);
                else
                    bb = bv[ii];
                f32x4 y = acc + bb;
                if (RELU) {
                    y[0] = fmaxf(y[0], 0.f); y[1] = fmaxf(y[1], 0.f);
                    y[2] = fmaxf(y[2], 0.f); y[3] = fmaxf(y[3], 0.f);
                }
                if (fb < CLW) {
                    f16x4 o = { (_Float16)y[0], (_Float16)y[1],
                                (_Float16)y[2], (_Float16)y[3] };
                    *(f16x4*)(Y + token * Ys + fb) = o;
                }
            }
        }
    }
}

// ---------------------------------------------------------------------------
// Fully-static paired-mt GEMM. Wave wv -> pair p=wv>>1 owns mts {2p, 2p+1};
// h=wv&1 owns nts {0,1,2} or {3,4} (static if/else, no breaks/ternaries).
// mt1 for pair 3 is tile 7 == GHOST when MTL==7: its W/bias reads land in the
// adjacent prep-initialized ws arrays (finite), its Y stores are killed by
// fb<CLW(112), its part column (7) is never summed. X read ONCE per (nt,kt),
// shared by both mts -> X LDS traffic 140 -> 80 b128 per block-phase.
// Bias loaded in epilogue (no cached bv arrays -> bounded registers).
// ---------------------------------------------------------------------------
template<bool RELU, int BMODE, int OMODE, int CLW>
__device__ __forceinline__ void pair_epi(f32x4 acc, int mt, int token, int kq,
                                         const float* __restrict__ biasp,
                                         const float* gbias,
                                         _Float16* Y, int Ys, float* part,
                                         const float* __restrict__ wa2p)
{
    const int fb = mt * 16 + kq * 4;
    if (OMODE == 2) {
        f32x4 y = acc + *(const f32x4*)(biasp + fb);
        y[0] = fmaxf(y[0], 0.f); y[1] = fmaxf(y[1], 0.f);
        y[2] = fmaxf(y[2], 0.f); y[3] = fmaxf(y[3], 0.f);
        f32x4 w4 = *(const f32x4*)(wa2p + fb);
        float p = y[0] * w4[0] + y[1] * w4[1] + y[2] * w4[2] + y[3] * w4[3];
        p += __shfl_xor(p, 16);
        p += __shfl_xor(p, 32);
        if (kq == 0) part[token * 8 + mt] = p;
    } else {
        f32x4 bb = (BMODE == 1)
            ? *(const f32x4*)(gbias + (token / NTOK) * 112 + fb)
            : *(const f32x4*)(biasp + fb);
        f32x4 y = acc + bb;
        if (RELU) {
            y[0] = fmaxf(y[0], 0.f); y[1] = fmaxf(y[1], 0.f);
            y[2] = fmaxf(y[2], 0.f); y[3] = fmaxf(y[3], 0.f);
        }
        if (fb < CLW) {
            f16x4 o = { (_Float16)y[0], (_Float16)y[1],
                        (_Float16)y[2], (_Float16)y[3] };
            *(f16x4*)(Y + token * Ys + fb) = o;
        }
    }
}

template<int KT, bool RELU, int BMODE, int OMODE, int CLW>
__device__ __forceinline__ void gemm_pair(const _Float16* X, const int Xs,
                                          const _Float16* __restrict__ WT, const int Bs,
                                          const float* __restrict__ biasp,
                                          const float* gbias,
                                          _Float16* Y, const int Ys,
                                          float* part, const float* __restrict__ wa2p,
                                          const int wv, const int lane)
{
    const int cl = lane & 15, kq = lane >> 4;
    const int p = wv >> 1, h = wv & 1;
    const int mt0 = 2 * p, mt1 = 2 * p + 1;
    f16x8 w0[KT], w1[KT];
    {
        const _Float16* Wp0 = WT + (mt0 * 16 + cl) * Bs + kq * 8;
        const _Float16* Wp1 = WT + (mt1 * 16 + cl) * Bs + kq * 8;
#pragma unroll
        for (int kt = 0; kt < KT; ++kt) {
            w0[kt] = *(const f16x8*)(Wp0 + kt * 32);
            w1[kt] = *(const f16x8*)(Wp1 + kt * 32);
        }
    }
    auto do_nt = [&](int nt) {
        const _Float16* Xp = X + (nt * 16 + cl) * Xs + kq * 8;
        f16x8 xf[KT];
#pragma unroll
        for (int kt = 0; kt < KT; ++kt) xf[kt] = *(const f16x8*)(Xp + kt * 32);
        f32x4 a0 = {0.f, 0.f, 0.f, 0.f}, a1 = {0.f, 0.f, 0.f, 0.f};
#pragma unroll
        for (int kt = 0; kt < KT; ++kt) {
            a0 = __builtin_amdgcn_mfma_f32_16x16x32_f16(w0[kt], xf[kt], a0, 0, 0, 0);
            a1 = __builtin_amdgcn_mfma_f32_16x16x32_f16(w1[kt], xf[kt], a1, 0, 0, 0);
        }
        const int token = nt * 16 + cl;
        pair_epi<RELU, BMODE, OMODE, CLW>(a0, mt0, token, kq, biasp, gbias, Y, Ys, part, wa2p);
        pair_epi<RELU, BMODE, OMODE, CLW>(a1, mt1, token, kq, biasp, gbias, Y, Ys, part, wa2p);
    };
    if (h == 0) { do_nt(0); do_nt(1); do_nt(2); }
    else        { do_nt(3); do_nt(4); }
}

// ===========================================================================
// MAIN kernel: static paired-mt heavy phases, raw lgkm barriers.
// ===========================================================================
__global__ __launch_bounds__(NT, 6)
void vnet_kernel(const float* __restrict__ x,
                 const float* __restrict__ ba2,
                 const _Float16* __restrict__ wsh,
                 _Float16* __restrict__ mvg)
{
    extern __shared__ float lds_f[];
    _Float16* lds_h = (_Float16*)lds_f;

    const int tid  = threadIdx.x;
    const int lane = tid & 63, wv = tid >> 6;
    const int b0   = blockIdx.x * GB;
    const float* wb = (const float*)wsh + WB_BASE;

    _Float16* xa  = lds_h + LH_C;
    _Float16* gqh = lds_h + LH_GQ;
    _Float16* h1w = lds_h + LH_H1;
    float* gbias = lds_f + LF_GB;
    float* att   = lds_f + LF_ATT;
    float* ss    = lds_f + LF_SS;
    float* part  = lds_f + LF_PART;

    // ---- P1: x -> C [token][40]; targeted pad zeroing --------------------
    const float* xg = x + (size_t)b0 * (NTOK * 13);
    for (int t = tid; t < GB * NTOK * 13; t += NT) {
        int row = t / 13, d = t - row * 13;
        xa[row * 40 + d] = (_Float16)xg[t];
    }
    for (int t = tid; t < 80 * 27; t += NT) {
        int row = t / 27, c = 13 + (t - row * 27);
        xa[row * 40 + c] = (_Float16)0.f;
    }
    for (int t = tid; t < 80 * 24; t += NT) {
        int row = t / 24, c = 112 + (t - row * 24);
        h1w[row * 136 + c] = (_Float16)0.f;
    }
    if (tid < 8) h1w[tid] = (_Float16)0.f;
    if (tid < GB * 6) {
        int b = tid / 6, d = tid - b * 6;
        ss[tid] = xg[b * (NTOK * 13) + d];   // x[b,0,d]
    }
    PHASE_BAR();

    // ---- P2: t1 = relu(x @ w1a + b1a) -> A [80][152] ---------------------
    gemm_sw<1, 10, NTT_P, true, 0, 0, 152, 8>(xa, 40, wsh + WS_W1A, 32,
        wb + WB_B1A, nullptr, lds_h + LH_T1, 152, nullptr, nullptr, wv, lane);
    PHASE_BAR();

    // ---- P3: h1 = relu(t1 @ w1b + b1b) -> B [80][136] --------------------
    gemm_sw<5, 7, NTT_P, true, 0, 0, 10000, 8>(lds_h + LH_T1, 152, wsh + WS_W1B,
        160, wb + WB_B1B, nullptr, h1w, 136, nullptr, nullptr, wv, lane);
    PHASE_BAR();

    // ---- P4: gq strip (u32-paired reads) ---------------------------------
    const _Float16* h1 = h1w;
    const uint* h1u = (const uint*)h1;
    for (int t = tid; t < GB * 50; t += NT) {
        int b = t / 50, cp = t - b * 50;
        float s0 = 0.f, s1 = 0.f;
#pragma unroll
        for (int n = 0; n < NTOK; ++n) {
            uint v = h1u[(b * NTOK + n) * 68 + cp];
            f16x2 pq = *(const f16x2*)&v;
            s0 += (float)pq.x; s1 += (float)pq.y;
        }
        f16x2 g = { (_Float16)(s0 * 0.05f), (_Float16)(s1 * 0.05f) };
        *(f16x2*)(gqh + b * 136 + 2 * cp) = g;
    }
    PHASE_BAR();

    // ---- Mg: gbias = ba0 + gq @ wa0_hi (f32 out) -------------------------
    gemm_sw<4, 7, 1, false, 0, 1, 10000, 8>(gqh, 136, wsh + WS_WA0H, 128,
        wb + WB_BA0, nullptr, (_Float16*)gbias, 0, nullptr, nullptr, wv, lane);
    PHASE_BAR();

    // ---- M1: s1 = relu(h1 @ wa0_lo + gbias) -> A (static paired) ---------
    gemm_pair<4, true, 1, 0, 112>(h1, 136, wsh + WS_WA0, 128, nullptr, gbias,
        lds_h + LH_S1, 136, nullptr, nullptr, wv, lane);
    PHASE_BAR();

    // ---- M2: s2-scores partials from s1 (static paired, no s2 store) -----
    gemm_pair<4, true, 0, 2, 112>(lds_h + LH_S1, 136, wsh + WS_WA1, 128,
        wb + WB_BA1, nullptr, nullptr, 0, part, wb + WB_WA2, wv, lane);
    PHASE_BAR();

    // ---- M3: f1 = relu(h1 @ w2a + b2a) -> A (static paired) --------------
    gemm_pair<4, true, 0, 0, 112>(h1, 136, wsh + WS_W2A, 128, wb + WB_B2A,
        nullptr, lds_h + LH_F1, 136, nullptr, nullptr, wv, lane);
    PHASE_BAR();

    // ---- M4: f = f1 @ w2b + b2b -> B head (waves 0-3); softmax (4-7) -----
    if (wv < 4) {
        gemm_sw<4, 4, NTT_P, false, 0, 0, 10000, 4>(lds_h + LH_F1, 136,
            wsh + WS_W2B, 128, wb + WB_B2B, nullptr, lds_h + LH_FF, 72,
            nullptr, nullptr, wv, lane);
    } else {
        const int b = wv - 4;
        float sc = -1e30f;
        if (lane < NTOK) {
            sc = ba2[0];
            const float* pr = part + (b * NTOK + lane) * 8;
#pragma unroll
            for (int m = 0; m < 7; ++m) sc += pr[m];
        }
        float mx = sc;
#pragma unroll
        for (int off = 16; off; off >>= 1) mx = fmaxf(mx, __shfl_xor(mx, off, 32));
        float e = (lane < NTOK) ? expf(sc - mx) : 0.f;
        float s = e;
#pragma unroll
        for (int off = 16; off; off >>= 1) s += __shfl_xor(s, off, 32);
        if (lane < NTOK) att[b * NTOK + lane] = e / s;
    }
    PHASE_BAR();

    // ---- P10: mv[b][c] = [ss | wf | 0-pad] -> GLOBAL fp16 [B][64] --------
    const _Float16* fh = lds_h + LH_FF;
    for (int t = tid; t < GB * 64; t += NT) {
        int b = t >> 6, c = t & 63;
        float v = 0.f;
        if (c < 6) {
            v = ss[b * 6 + c];
        } else if (c < 56) {
            const int cc = c - 6;
            const float* ab = att + b * NTOK;
            float acc = 0.f;
#pragma unroll
            for (int n = 0; n < NTOK; ++n)
                acc = fmaf((float)fh[(b * NTOK + n) * 72 + cc], ab[n], acc);
            v = acc;
        }
        mvg[(size_t)(b0 + b) * 64 + c] = (_Float16)v;
    }
}

// ===========================================================================
// TAIL kernel (unchanged from R16): 64 batches/block, W-prefetch ping.
// ===========================================================================
template<int KT, int MTL, int NW>
struct WC {
    static constexpr int IPW = (MTL + NW - 1) / NW;
    f16x8 wf[IPW][KT];
    f32x4 bv[IPW];
};

template<int KT, int MTL, int NW, bool LOADB>
__device__ __forceinline__ void load_w(WC<KT, MTL, NW>& W,
                                       const _Float16* __restrict__ WT, const int Bs,
                                       const float* __restrict__ biasp,
                                       const int wv, const int lane)
{
    const int cl = lane & 15, kq = lane >> 4;
#pragma unroll
    for (int ii = 0; ii < WC<KT, MTL, NW>::IPW; ++ii) {
        const int mt = wv + ii * NW;
        if (mt < MTL) {
            const _Float16* Wp = WT + (mt * 16 + cl) * Bs + kq * 8;
#pragma unroll
            for (int kt = 0; kt < KT; ++kt) W.wf[ii][kt] = *(const f16x8*)(Wp + kt * 32);
            if (LOADB) W.bv[ii] = *(const f32x4*)(biasp + mt * 16 + kq * 4);
        }
    }
}

template<int KT, int MTL, int NTT, bool RELU, int NW>
__device__ __forceinline__ void gemm_wc(const WC<KT, MTL, NW>& W,
                                        const _Float16* X, const int Xs,
                                        _Float16* Y, const int Ys,
                                        const int wv, const int lane)
{
    const int cl = lane & 15, kq = lane >> 4;
#pragma unroll
    for (int ii = 0; ii < WC<KT, MTL, NW>::IPW; ++ii) {
        const int mt = wv + ii * NW;
        if (mt >= MTL) break;
        const int fb = mt * 16 + kq * 4;
#pragma unroll
        for (int nt = 0; nt < NTT; ++nt) {
            const _Float16* Xp = X + (nt * 16 + cl) * Xs + kq * 8;
            f16x8 xf[KT];
#pragma unroll
            for (int kt = 0; kt < KT; ++kt) xf[kt] = *(const f16x8*)(Xp + kt * 32);
            f32x4 acc = {0.f, 0.f, 0.f, 0.f};
#pragma unroll
            for (int kt = 0; kt < KT; ++kt)
                acc = __builtin_amdgcn_mfma_f32_16x16x32_f16(W.wf[ii][kt], xf[kt], acc, 0, 0, 0);
            const int token = nt * 16 + cl;
            f32x4 y = acc + W.bv[ii];
            if (RELU) {
                y[0] = fmaxf(y[0], 0.f); y[1] = fmaxf(y[1], 0.f);
                y[2] = fmaxf(y[2], 0.f); y[3] = fmaxf(y[3], 0.f);
            }
            f16x4 o = { (_Float16)y[0], (_Float16)y[1],
                        (_Float16)y[2], (_Float16)y[3] };
            *(f16x4*)(Y + token * Ys + fb) = o;
        }
    }
}

__global__ __launch_bounds__(NT)
void tail_kernel(const _Float16* __restrict__ mvg,
                 const float* __restrict__ w3d, const float* __restrict__ b3d,
                 const _Float16* __restrict__ wsh,
                 float* __restrict__ outp)
{
    extern __shared__ float lds_f[];
    _Float16* lds_h = (_Float16*)lds_f;

    const int tid  = threadIdx.x;
    const int lane = tid & 63, wv = tid >> 6;
    const int g0   = blockIdx.x * TB;
    const float* wb = (const float*)wsh + WB_BASE;

    WC<2, 10, 8> Wt1; WC<5, 7, 8> Wt2; WC<4, 7, 8> Wt3;
    load_w<2, 10, 8, true>(Wt1, wsh + WS_W3A, 64, wb + WB_B3A, wv, lane);

    // ---- L: load mv -> LDS stride 72 -------------------------------------
    _Float16* mvT = lds_h + TL_MV;
    {
        const uint* src = (const uint*)(mvg + (size_t)g0 * 64);
        uint* dst = (uint*)mvT;
        for (int t = tid; t < TB * 32; t += NT) {
            int row = t >> 5, c = t & 31;
            dst[row * 36 + c] = src[t];
        }
    }
    for (int t = tid; t < (TL_HC - TL_HB) / 2; t += NT)
        ((uint*)(lds_h + TL_HB))[t] = 0u;
    __syncthreads();

    // ---- T1: ha = relu(mv @ w3a + b3a)  [64][168], K=64 ------------------
    load_w<5, 7, 8, true>(Wt2, wsh + WS_W3B, 160, wb + WB_B3B, wv, lane);
    gemm_wc<2, 10, 4, true, 8>(Wt1, mvT, 72, lds_h + TL_HA, 168, wv, lane);
    __syncthreads();

    // ---- T2: hb = relu(ha @ w3b + b3b)  [64][136], K=160 -----------------
    load_w<4, 7, 8, true>(Wt3, wsh + WS_W3C, 128, wb + WB_B3C, wv, lane);
    gemm_wc<5, 7, 4, true, 8>(Wt2, lds_h + TL_HA, 168, lds_h + TL_HB, 136, wv, lane);
    __syncthreads();

    // ---- T3: hc = relu(hb @ w3c + b3c)  [64][136], K=128 -----------------
    gemm_wc<4, 7, 4, true, 8>(Wt3, lds_h + TL_HB, 136, lds_h + TL_HC, 136, wv, lane);
    __syncthreads();

    // ---- T4: out = hc . w3d + b3d  (8 lanes per batch) -------------------
    {
        const int b = tid >> 3, kl = tid & 7;
        const _Float16* hc = lds_h + TL_HC + b * 136;
        float acc = 0.f;
#pragma unroll 13
        for (int k = kl; k < 100; k += 8)
            acc = fmaf((float)hc[k], w3d[k], acc);
        acc += __shfl_xor(acc, 1);
        acc += __shfl_xor(acc, 2);
        acc += __shfl_xor(acc, 4);
        if (kl == 0) outp[g0 + b] = acc + b3d[0];
    }
}

extern "C" void kernel_launch(void* const* d_in, const int* in_sizes, int n_in,
                              void* d_out, int out_size, void* d_ws, size_t ws_size,
                              hipStream_t stream)
{
    const float* x   = (const float*)d_in[0];
    const float* w1a = (const float*)d_in[1];
    const float* b1a = (const float*)d_in[2];
    const float* w1b = (const float*)d_in[3];
    const float* b1b = (const float*)d_in[4];
    const float* wa0 = (const float*)d_in[5];
    const float* ba0 = (const float*)d_in[6];
    const float* wa1 = (const float*)d_in[7];
    const float* ba1 = (const float*)d_in[8];
    const float* wa2 = (const float*)d_in[9];
    const float* ba2 = (const float*)d_in[10];
    const float* w2a = (const float*)d_in[11];
    const float* b2a = (const float*)d_in[12];
    const float* w2b = (const float*)d_in[13];
    const float* b2b = (const float*)d_in[14];
    const float* w3a = (const float*)d_in[15];
    const float* b3a = (const float*)d_in[16];
    const float* w3b = (const float*)d_in[17];
    const float* b3b = (const float*)d_in[18];
    const float* w3c = (const float*)d_in[19];
    const float* b3c = (const float*)d_in[20];
    const float* w3d = (const float*)d_in[21];
    const float* b3d = (const float*)d_in[22];
    float* outp = (float*)d_out;
    _Float16* wsh = (_Float16*)d_ws;
    _Float16* mvg = wsh + WS_MV;

    hipFuncSetAttribute((const void*)vnet_kernel,
                        hipFuncAttributeMaxDynamicSharedMemorySize, LDS_BYTES);
    hipFuncSetAttribute((const void*)tail_kernel,
                        hipFuncAttributeMaxDynamicSharedMemorySize, LDS_T_BYTES);

    hipLaunchKernelGGL(prep_kernel, dim3((PREP_TOTAL + 255) / 256), dim3(256),
                       0, stream,
                       w1a, w1b, wa0, wa1, w2a, w2b, w3a, w3b, w3c, wa2,
                       b1a, b1b, ba0, ba1, b2a, b2b, b3a, b3b, b3c, wsh);

    const int B = 16384;
    hipLaunchKernelGGL(vnet_kernel, dim3(B / GB), dim3(NT), LDS_BYTES, stream,
                       x, ba2, wsh, mvg);
    hipLaunchKernelGGL(tail_kernel, dim3(B / TB), dim3(NT), LDS_T_BYTES, stream,
                       mvg, w3d, b3d, wsh, outp);
}

// Round 19
// 115.759 us; speedup vs baseline: 1.7057x; 1.6226x over previous
//
#include <hip/hip_runtime.h>
#include <math.h>

#define NT     512
#define NWAVES 8
#define GB     4
#define NTOK   20
#define NTT_P  5          // token tiles for 80-row phases

typedef _Float16 f16x8 __attribute__((ext_vector_type(8)));
typedef _Float16 f16x4 __attribute__((ext_vector_type(4)));
typedef _Float16 f16x2 __attribute__((ext_vector_type(2)));
typedef float    f32x4 __attribute__((ext_vector_type(4)));

// Raw phase barrier: LDS-visibility only (proven R15/R16).
#define PHASE_BAR() do {                                      \
    asm volatile("s_waitcnt lgkmcnt(0)" ::: "memory");        \
    __builtin_amdgcn_s_barrier();                             \
    asm volatile("" ::: "memory");                            \
    __builtin_amdgcn_sched_barrier(0);                        \
} while (0)

// Wave-local LDS fence (no s_barrier): orders this wave's ds_writes before
// its own subsequent ds_reads. Used for the Mg->M1 fold where producer and
// consumer are the SAME wave. sched_barrier per guide rule #18.
#define WAVE_BAR() do {                                       \
    asm volatile("s_waitcnt lgkmcnt(0)" ::: "memory");        \
    asm volatile("" ::: "memory");                            \
    __builtin_amdgcn_sched_barrier(0);                        \
} while (0)

// ---- ws fp16 section: transposed, zero-padded weights W_T[n][kpad] --------
#define WS_W1A  0        // [160][32]   (N=150,K=13)
#define WS_W1B  5120     // [112][160]  (N=100,K=150)
#define WS_WA0  23040    // [112][128]  wa0 rows 0..99
#define WS_WA1  37376    // [112][128]
#define WS_W2A  51712    // [112][128]
#define WS_W2B  66048    // [64][128]   (N=50,K=100)
#define WS_W3A  74240    // [160][64]   (N=150,K=56)
#define WS_W3B  84480    // [112][160]  (N=100,K=150)
#define WS_W3C  102400   // [112][128]  (N=100,K=100)
#define WS_WA0H 116736   // [112][128]  wa0 rows 100..199 (g part)
#define WS_TOTAL 131072
// ---- ws f32 bias section (zero-padded) ------------------------------------
#define WB_BASE 65536
#define WB_B1A  0
#define WB_B1B  160
#define WB_BA0  272
#define WB_BA1  384
#define WB_B2A  496
#define WB_B2B  608
#define WB_B3A  672
#define WB_B3B  832
#define WB_B3C  944
#define WB_WA2  1056
#define WB_N    1168
#define PREP_TOTAL (WS_TOTAL + WB_N)
// ---- mv staging: fp16 [B][64] ---------------------------------------------
#define WS_MV   135168

// ---- main-kernel LDS arena (halves), 52.9 KB -> 3 blocks/CU ---------------
#define LH_A    0
#define LH_B    12160
#define LH_C    23040
#define LH_T1   LH_A          // stride 152
#define LH_S1   LH_A          // stride 136
#define LH_F1   LH_A          // stride 136
#define LH_H1   LH_B          // stride 136
#define LH_FF   LH_B          // [80][72]
#define LH_GQ   LH_C          // [16][136] strip
#define LF_PART 11520         // f32: part [80][8]
#define LF_GB   12672         // f32: gbias [4][112]
#define LF_ATT  13120         // f32: att [80]
#define LF_SS   13200         // f32: ss [24]
#define LDS_DW  13224
#define LDS_BYTES (LDS_DW * 4)

// ---- tail-kernel LDS arena (halves) ---------------------------------------
#define TB      64
#define TL_MV   0        // [64][72]
#define TL_HA   4608     // [64][168]
#define TL_HB   15360    // [64][136]
#define TL_HC   24064    // [64][136]
#define LDS_T_DW   16384
#define LDS_T_BYTES (LDS_T_DW * 4)

// ---------------------------------------------------------------------------
// prep
// ---------------------------------------------------------------------------
__device__ __forceinline__ void prep_one(const float* __restrict__ src, _Float16* dst,
                                         int local, int N, int K, int Ks)
{
    int n = local / Ks, k = local - n * Ks;
    dst[local] = (_Float16)((n < N && k < K) ? src[k * N + n] : 0.f);
}
__device__ __forceinline__ void prep_b(const float* __restrict__ src, float* dst,
                                       int idx, int N)
{
    dst[idx] = (idx < N) ? src[idx] : 0.f;
}

__global__ __launch_bounds__(256)
void prep_kernel(const float* __restrict__ w1a, const float* __restrict__ w1b,
                 const float* __restrict__ wa0, const float* __restrict__ wa1,
                 const float* __restrict__ w2a, const float* __restrict__ w2b,
                 const float* __restrict__ w3a, const float* __restrict__ w3b,
                 const float* __restrict__ w3c, const float* __restrict__ wa2,
                 const float* __restrict__ b1a, const float* __restrict__ b1b,
                 const float* __restrict__ ba0, const float* __restrict__ ba1,
                 const float* __restrict__ b2a, const float* __restrict__ b2b,
                 const float* __restrict__ b3a, const float* __restrict__ b3b,
                 const float* __restrict__ b3c,
                 _Float16* __restrict__ ws)
{
    int g = blockIdx.x * 256 + threadIdx.x;
    if (g >= PREP_TOTAL) return;
    if (g >= WS_TOTAL) {
        float* wb = (float*)ws + WB_BASE;
        int l = g - WS_TOTAL;
        if (l < WB_B1B)      prep_b(b1a, wb + WB_B1A, l - WB_B1A, 150);
        else if (l < WB_BA0) prep_b(b1b, wb + WB_B1B, l - WB_B1B, 100);
        else if (l < WB_BA1) prep_b(ba0, wb + WB_BA0, l - WB_BA0, 100);
        else if (l < WB_B2A) prep_b(ba1, wb + WB_BA1, l - WB_BA1, 100);
        else if (l < WB_B2B) prep_b(b2a, wb + WB_B2A, l - WB_B2A, 100);
        else if (l < WB_B3A) prep_b(b2b, wb + WB_B2B, l - WB_B2B, 50);
        else if (l < WB_B3B) prep_b(b3a, wb + WB_B3A, l - WB_B3A, 150);
        else if (l < WB_B3C) prep_b(b3b, wb + WB_B3B, l - WB_B3B, 100);
        else if (l < WB_WA2) prep_b(b3c, wb + WB_B3C, l - WB_B3C, 100);
        else                 prep_b(wa2, wb + WB_WA2, l - WB_WA2, 100);
        return;
    }
    if (g < WS_W1B)       prep_one(w1a, ws + WS_W1A, g - WS_W1A, 150, 13, 32);
    else if (g < WS_WA0)  prep_one(w1b, ws + WS_W1B, g - WS_W1B, 100, 150, 160);
    else if (g < WS_WA1)  prep_one(wa0, ws + WS_WA0, g - WS_WA0, 100, 100, 128);
    else if (g < WS_W2A)  prep_one(wa1, ws + WS_WA1, g - WS_WA1, 100, 100, 128);
    else if (g < WS_W2B)  prep_one(w2a, ws + WS_W2A, g - WS_W2A, 100, 100, 128);
    else if (g < WS_W3A)  prep_one(w2b, ws + WS_W2B, g - WS_W2B,  50, 100, 128);
    else if (g < WS_W3B)  prep_one(w3a, ws + WS_W3A, g - WS_W3A, 150,  56, 64);
    else if (g < WS_W3C)  prep_one(w3b, ws + WS_W3B, g - WS_W3B, 100, 150, 160);
    else if (g < WS_WA0H) prep_one(w3c, ws + WS_W3C, g - WS_W3C, 100, 100, 128);
    else                  prep_one(wa0 + 100 * 100, ws + WS_WA0H, g - WS_WA0H, 100, 100, 128);
}

// ---------------------------------------------------------------------------
// W-fragment cache (prefetched one phase ahead where proven safe).
// ---------------------------------------------------------------------------
template<int KT, int MTL, int NW>
struct WC {
    static constexpr int IPW = (MTL + NW - 1) / NW;
    f16x8 wf[IPW][KT];
    f32x4 bv[IPW];
};

template<int KT, int MTL, int NW, bool LOADB>
__device__ __forceinline__ void load_w(WC<KT, MTL, NW>& W,
                                       const _Float16* __restrict__ WT, const int Bs,
                                       const float* __restrict__ biasp,
                                       const int wv, const int lane)
{
    const int cl = lane & 15, kq = lane >> 4;
#pragma unroll
    for (int ii = 0; ii < WC<KT, MTL, NW>::IPW; ++ii) {
        const int mt = wv + ii * NW;
        if (mt < MTL) {
            const _Float16* Wp = WT + (mt * 16 + cl) * Bs + kq * 8;
#pragma unroll
            for (int kt = 0; kt < KT; ++kt) W.wf[ii][kt] = *(const f16x8*)(Wp + kt * 32);
            if (LOADB) W.bv[ii] = *(const f32x4*)(biasp + mt * 16 + kq * 4);
        }
    }
}

// ---------------------------------------------------------------------------
// Compute part of the swapped-operand GEMM with preloaded W (R14/R16-proven).
// OMODE 0: fp16 Y[token][feat] b64 store, clamped fb<CLW.
// OMODE 1: f32x4 -> gbias[token][feat] (token<GB).
// OMODE 2: scores-partial (unused in gemm_c callers here).
// BMODE 0: bias from preloaded bv. 1: gbias[token/20][feat..].
// ---------------------------------------------------------------------------
template<int KT, int MTL, int NTT, bool RELU, int BMODE, int OMODE, int CLW, int NW>
__device__ __forceinline__ void gemm_c(const WC<KT, MTL, NW>& W,
                                       const _Float16* X, const int Xs,
                                       const float* gbias,
                                       _Float16* Y, const int Ys,
                                       float* part, const float* __restrict__ wa2p,
                                       const int wv, const int lane)
{
    const int cl = lane & 15, kq = lane >> 4;
#pragma unroll
    for (int ii = 0; ii < WC<KT, MTL, NW>::IPW; ++ii) {
        const int mt = wv + ii * NW;
        if (mt >= MTL) break;
        const int fb = mt * 16 + kq * 4;
#pragma unroll
        for (int nt = 0; nt < NTT; ++nt) {
            const _Float16* Xp = X + (nt * 16 + cl) * Xs + kq * 8;
            f16x8 xf[KT];
#pragma unroll
            for (int kt = 0; kt < KT; ++kt) xf[kt] = *(const f16x8*)(Xp + kt * 32);
            f32x4 acc = {0.f, 0.f, 0.f, 0.f};
#pragma unroll
            for (int kt = 0; kt < KT; ++kt)
                acc = __builtin_amdgcn_mfma_f32_16x16x32_f16(W.wf[ii][kt], xf[kt], acc, 0, 0, 0);
            const int token = nt * 16 + cl;
            if (OMODE == 1) {
                if (cl < GB) {
                    f32x4 o = acc + W.bv[ii];
                    *(f32x4*)((float*)Y + cl * 112 + fb) = o;
                }
            } else if (OMODE == 2) {
                f32x4 y = acc + W.bv[ii];
                y[0] = fmaxf(y[0], 0.f); y[1] = fmaxf(y[1], 0.f);
                y[2] = fmaxf(y[2], 0.f); y[3] = fmaxf(y[3], 0.f);
                f32x4 w4 = *(const f32x4*)(wa2p + fb);
                float p = y[0] * w4[0] + y[1] * w4[1] + y[2] * w4[2] + y[3] * w4[3];
                p += __shfl_xor(p, 16);
                p += __shfl_xor(p, 32);
                if (kq == 0) part[token * 8 + mt] = p;
            } else {
                f32x4 bb;
                if (BMODE == 1)
                    bb = *(const f32x4*)(gbias + (token / NTOK) * 112 + fb);
                else
                    bb = W.bv[ii];
                f32x4 y = acc + bb;
                if (RELU) {
                    y[0] = fmaxf(y[0], 0.f); y[1] = fmaxf(y[1], 0.f);
                    y[2] = fmaxf(y[2], 0.f); y[3] = fmaxf(y[3], 0.f);
                }
                if (fb < CLW) {
                    f16x4 o = { (_Float16)y[0], (_Float16)y[1],
                                (_Float16)y[2], (_Float16)y[3] };
                    *(f16x4*)(Y + token * Ys + fb) = o;
                }
            }
        }
    }
}

// ---------------------------------------------------------------------------
// Monolithic swapped-operand GEMM (R12-proven): W loaded in-phase.
// ---------------------------------------------------------------------------
template<int KT, int MTL, int NTT, bool RELU, int BMODE, int OMODE, int CLW, int NW>
__device__ __forceinline__ void gemm_sw(const _Float16* X, const int Xs,
                                        const _Float16* __restrict__ WT, const int Bs,
                                        const float* __restrict__ biasp,
                                        const float* gbias,
                                        _Float16* Y, const int Ys,
                                        float* part, const float* __restrict__ wa2p,
                                        const int wv, const int lane)
{
    WC<KT, MTL, NW> W;
    load_w<KT, MTL, NW, true>(W, WT, Bs, biasp ? biasp : (const float*)WT, wv, lane);
    gemm_c<KT, MTL, NTT, RELU, BMODE, OMODE, CLW, NW>(W, X, Xs, gbias, Y, Ys,
                                                      part, wa2p, wv, lane);
}

// ===========================================================================
// MAIN kernel: 9 phases. Mg folded into M1 (wave-local dependency).
// ===========================================================================
__global__ __launch_bounds__(NT, 6)
void vnet_kernel(const float* __restrict__ x,
                 const float* __restrict__ ba2,
                 const _Float16* __restrict__ wsh,
                 _Float16* __restrict__ mvg)
{
    extern __shared__ float lds_f[];
    _Float16* lds_h = (_Float16*)lds_f;

    const int tid  = threadIdx.x;
    const int lane = tid & 63, wv = tid >> 6;
    const int b0   = blockIdx.x * GB;
    const float* wb = (const float*)wsh + WB_BASE;

    _Float16* xa  = lds_h + LH_C;
    _Float16* gqh = lds_h + LH_GQ;
    _Float16* h1w = lds_h + LH_H1;
    float* gbias = lds_f + LF_GB;
    float* att   = lds_f + LF_ATT;
    float* ss    = lds_f + LF_SS;
    float* part  = lds_f + LF_PART;

    WC<1, 10, 8> Wp2;   // w1a
    WC<5, 7, 8>  Wp3;   // w1b
    WC<4, 7, 8>  Wg;    // wa0_hi (gbias MFMA)
    WC<4, 7, 8>  Wm1;   // wa0_lo (bias via gbias)

    // ---- P1: prefetch W(P2); x -> C [token][40]; targeted pad zeroing ----
    load_w<1, 10, 8, true>(Wp2, wsh + WS_W1A, 32, wb + WB_B1A, wv, lane);
    const float* xg = x + (size_t)b0 * (NTOK * 13);
    for (int t = tid; t < GB * NTOK * 13; t += NT) {
        int row = t / 13, d = t - row * 13;
        xa[row * 40 + d] = (_Float16)xg[t];
    }
    for (int t = tid; t < 80 * 27; t += NT) {
        int row = t / 27, c = 13 + (t - row * 27);
        xa[row * 40 + c] = (_Float16)0.f;
    }
    for (int t = tid; t < 80 * 24; t += NT) {
        int row = t / 24, c = 112 + (t - row * 24);
        h1w[row * 136 + c] = (_Float16)0.f;
    }
    if (tid < 8) h1w[tid] = (_Float16)0.f;
    if (tid < GB * 6) {
        int b = tid / 6, d = tid - b * 6;
        ss[tid] = xg[b * (NTOK * 13) + d];   // x[b,0,d]
    }
    PHASE_BAR();

    // ---- P2: t1 = relu(x @ w1a + b1a) -> A [80][152]; prefetch w1b -------
    load_w<5, 7, 8, true>(Wp3, wsh + WS_W1B, 160, wb + WB_B1B, wv, lane);
    gemm_c<1, 10, NTT_P, true, 0, 0, 152, 8>(Wp2, xa, 40, nullptr,
        lds_h + LH_T1, 152, nullptr, nullptr, wv, lane);
    PHASE_BAR();

    // ---- P3: h1 = relu(t1 @ w1b + b1b) -> B [80][136] --------------------
    gemm_c<5, 7, NTT_P, true, 0, 0, 10000, 8>(Wp3, lds_h + LH_T1, 152, nullptr,
        h1w, 136, nullptr, nullptr, wv, lane);
    PHASE_BAR();

    // ---- P4: gq strip; prefetch Wg = wa0_hi and Wm1 = wa0_lo -------------
    load_w<4, 7, 8, true>(Wg, wsh + WS_WA0H, 128, wb + WB_BA0, wv, lane);
    load_w<4, 7, 8, false>(Wm1, wsh + WS_WA0, 128, nullptr, wv, lane);
    const _Float16* h1 = h1w;
    const uint* h1u = (const uint*)h1;
    for (int t = tid; t < GB * 50; t += NT) {
        int b = t / 50, cp = t - b * 50;
        float s0 = 0.f, s1 = 0.f;
#pragma unroll
        for (int n = 0; n < NTOK; ++n) {
            uint v = h1u[(b * NTOK + n) * 68 + cp];
            f16x2 pq = *(const f16x2*)&v;
            s0 += (float)pq.x; s1 += (float)pq.y;
        }
        f16x2 g = { (_Float16)(s0 * 0.05f), (_Float16)(s1 * 0.05f) };
        *(f16x2*)(gqh + b * 136 + 2 * cp) = g;
    }
    PHASE_BAR();

    // ---- M1': fused gbias + s1. Wave wv computes gbias cols [wv*16,wv*16+16)
    //           (Mg MFMA, writes its own gbias slice), wave-local fence, then
    //           s1 = relu(h1 @ wa0_lo + gbias) reading ONLY its own slice. --
    gemm_c<4, 7, 1, false, 0, 1, 10000, 8>(Wg, gqh, 136, nullptr,
        (_Float16*)gbias, 0, nullptr, nullptr, wv, lane);
    WAVE_BAR();
    gemm_c<4, 7, NTT_P, true, 1, 0, 10000, 8>(Wm1, h1, 136, gbias,
        lds_h + LH_S1, 136, nullptr, nullptr, wv, lane);
    PHASE_BAR();

    // ---- M2: s2-scores partials from s1 (no s2 store) -> part ------------
    gemm_sw<4, 7, NTT_P, true, 0, 2, 10000, 8>(lds_h + LH_S1, 136, wsh + WS_WA1,
        128, wb + WB_BA1, nullptr, nullptr, 0, part, wb + WB_WA2, wv, lane);
    PHASE_BAR();

    // ---- M3: f1 = relu(h1 @ w2a + b2a) -> A (s1 dead) --------------------
    gemm_sw<4, 7, NTT_P, true, 0, 0, 10000, 8>(h1, 136, wsh + WS_W2A, 128,
        wb + WB_B2A, nullptr, lds_h + LH_F1, 136, nullptr, nullptr, wv, lane);
    PHASE_BAR();

    // ---- M4: f = f1 @ w2b + b2b -> B head (waves 0-3); softmax (4-7) -----
    if (wv < 4) {
        gemm_sw<4, 4, NTT_P, false, 0, 0, 10000, 4>(lds_h + LH_F1, 136,
            wsh + WS_W2B, 128, wb + WB_B2B, nullptr, lds_h + LH_FF, 72,
            nullptr, nullptr, wv, lane);
    } else {
        const int b = wv - 4;
        float sc = -1e30f;
        if (lane < NTOK) {
            sc = ba2[0];
            const float* pr = part + (b * NTOK + lane) * 8;
#pragma unroll
            for (int m = 0; m < 7; ++m) sc += pr[m];
        }
        float mx = sc;
#pragma unroll
        for (int off = 16; off; off >>= 1) mx = fmaxf(mx, __shfl_xor(mx, off, 32));
        float e = (lane < NTOK) ? expf(sc - mx) : 0.f;
        float s = e;
#pragma unroll
        for (int off = 16; off; off >>= 1) s += __shfl_xor(s, off, 32);
        if (lane < NTOK) att[b * NTOK + lane] = e / s;
    }
    PHASE_BAR();

    // ---- P10: mv[b][c] = [ss | wf | 0-pad] -> GLOBAL fp16 [B][64] --------
    const _Float16* fh = lds_h + LH_FF;
    for (int t = tid; t < GB * 64; t += NT) {
        int b = t >> 6, c = t & 63;
        float v = 0.f;
        if (c < 6) {
            v = ss[b * 6 + c];
        } else if (c < 56) {
            const int cc = c - 6;
            const float* ab = att + b * NTOK;
            float acc = 0.f;
#pragma unroll
            for (int n = 0; n < NTOK; ++n)
                acc = fmaf((float)fh[(b * NTOK + n) * 72 + cc], ab[n], acc);
            v = acc;
        }
        mvg[(size_t)(b0 + b) * 64 + c] = (_Float16)v;
    }
}

// ===========================================================================
// TAIL kernel (unchanged from R16): 64 batches/block, W-prefetch ping.
// ===========================================================================
template<int KT, int MTL, int NTT, bool RELU, int NW>
__device__ __forceinline__ void gemm_wc(const WC<KT, MTL, NW>& W,
                                        const _Float16* X, const int Xs,
                                        _Float16* Y, const int Ys,
                                        const int wv, const int lane)
{
    const int cl = lane & 15, kq = lane >> 4;
#pragma unroll
    for (int ii = 0; ii < WC<KT, MTL, NW>::IPW; ++ii) {
        const int mt = wv + ii * NW;
        if (mt >= MTL) break;
        const int fb = mt * 16 + kq * 4;
#pragma unroll
        for (int nt = 0; nt < NTT; ++nt) {
            const _Float16* Xp = X + (nt * 16 + cl) * Xs + kq * 8;
            f16x8 xf[KT];
#pragma unroll
            for (int kt = 0; kt < KT; ++kt) xf[kt] = *(const f16x8*)(Xp + kt * 32);
            f32x4 acc = {0.f, 0.f, 0.f, 0.f};
#pragma unroll
            for (int kt = 0; kt < KT; ++kt)
                acc = __builtin_amdgcn_mfma_f32_16x16x32_f16(W.wf[ii][kt], xf[kt], acc, 0, 0, 0);
            const int token = nt * 16 + cl;
            f32x4 y = acc + W.bv[ii];
            if (RELU) {
                y[0] = fmaxf(y[0], 0.f); y[1] = fmaxf(y[1], 0.f);
                y[2] = fmaxf(y[2], 0.f); y[3] = fmaxf(y[3], 0.f);
            }
            f16x4 o = { (_Float16)y[0], (_Float16)y[1],
                        (_Float16)y[2], (_Float16)y[3] };
            *(f16x4*)(Y + token * Ys + fb) = o;
        }
    }
}

__global__ __launch_bounds__(NT)
void tail_kernel(const _Float16* __restrict__ mvg,
                 const float* __restrict__ w3d, const float* __restrict__ b3d,
                 const _Float16* __restrict__ wsh,
                 float* __restrict__ outp)
{
    extern __shared__ float lds_f[];
    _Float16* lds_h = (_Float16*)lds_f;

    const int tid  = threadIdx.x;
    const int lane = tid & 63, wv = tid >> 6;
    const int g0   = blockIdx.x * TB;
    const float* wb = (const float*)wsh + WB_BASE;

    WC<2, 10, 8> Wt1; WC<5, 7, 8> Wt2; WC<4, 7, 8> Wt3;
    load_w<2, 10, 8, true>(Wt1, wsh + WS_W3A, 64, wb + WB_B3A, wv, lane);

    // ---- L: load mv -> LDS stride 72 -------------------------------------
    _Float16* mvT = lds_h + TL_MV;
    {
        const uint* src = (const uint*)(mvg + (size_t)g0 * 64);
        uint* dst = (uint*)mvT;
        for (int t = tid; t < TB * 32; t += NT) {
            int row = t >> 5, c = t & 31;
            dst[row * 36 + c] = src[t];
        }
    }
    for (int t = tid; t < (TL_HC - TL_HB) / 2; t += NT)
        ((uint*)(lds_h + TL_HB))[t] = 0u;
    __syncthreads();

    // ---- T1: ha = relu(mv @ w3a + b3a)  [64][168], K=64 ------------------
    load_w<5, 7, 8, true>(Wt2, wsh + WS_W3B, 160, wb + WB_B3B, wv, lane);
    gemm_wc<2, 10, 4, true, 8>(Wt1, mvT, 72, lds_h + TL_HA, 168, wv, lane);
    __syncthreads();

    // ---- T2: hb = relu(ha @ w3b + b3b)  [64][136], K=160 -----------------
    load_w<4, 7, 8, true>(Wt3, wsh + WS_W3C, 128, wb + WB_B3C, wv, lane);
    gemm_wc<5, 7, 4, true, 8>(Wt2, lds_h + TL_HA, 168, lds_h + TL_HB, 136, wv, lane);
    __syncthreads();

    // ---- T3: hc = relu(hb @ w3c + b3c)  [64][136], K=128 -----------------
    gemm_wc<4, 7, 4, true, 8>(Wt3, lds_h + TL_HB, 136, lds_h + TL_HC, 136, wv, lane);
    __syncthreads();

    // ---- T4: out = hc . w3d + b3d  (8 lanes per batch) -------------------
    {
        const int b = tid >> 3, kl = tid & 7;
        const _Float16* hc = lds_h + TL_HC + b * 136;
        float acc = 0.f;
#pragma unroll 13
        for (int k = kl; k < 100; k += 8)
            acc = fmaf((float)hc[k], w3d[k], acc);
        acc += __shfl_xor(acc, 1);
        acc += __shfl_xor(acc, 2);
        acc += __shfl_xor(acc, 4);
        if (kl == 0) outp[g0 + b] = acc + b3d[0];
    }
}

extern "C" void kernel_launch(void* const* d_in, const int* in_sizes, int n_in,
                              void* d_out, int out_size, void* d_ws, size_t ws_size,
                              hipStream_t stream)
{
    const float* x   = (const float*)d_in[0];
    const float* w1a = (const float*)d_in[1];
    const float* b1a = (const float*)d_in[2];
    const float* w1b = (const float*)d_in[3];
    const float* b1b = (const float*)d_in[4];
    const float* wa0 = (const float*)d_in[5];
    const float* ba0 = (const float*)d_in[6];
    const float* wa1 = (const float*)d_in[7];
    const float* ba1 = (const float*)d_in[8];
    const float* wa2 = (const float*)d_in[9];
    const float* ba2 = (const float*)d_in[10];
    const float* w2a = (const float*)d_in[11];
    const float* b2a = (const float*)d_in[12];
    const float* w2b = (const float*)d_in[13];
    const float* b2b = (const float*)d_in[14];
    const float* w3a = (const float*)d_in[15];
    const float* b3a = (const float*)d_in[16];
    const float* w3b = (const float*)d_in[17];
    const float* b3b = (const float*)d_in[18];
    const float* w3c = (const float*)d_in[19];
    const float* b3c = (const float*)d_in[20];
    const float* w3d = (const float*)d_in[21];
    const float* b3d = (const float*)d_in[22];
    float* outp = (float*)d_out;
    _Float16* wsh = (_Float16*)d_ws;
    _Float16* mvg = wsh + WS_MV;

    hipFuncSetAttribute((const void*)vnet_kernel,
                        hipFuncAttributeMaxDynamicSharedMemorySize, LDS_BYTES);
    hipFuncSetAttribute((const void*)tail_kernel,
                        hipFuncAttributeMaxDynamicSharedMemorySize, LDS_T_BYTES);

    hipLaunchKernelGGL(prep_kernel, dim3((PREP_TOTAL + 255) / 256), dim3(256),
                       0, stream,
                       w1a, w1b, wa0, wa1, w2a, w2b, w3a, w3b, w3c, wa2,
                       b1a, b1b, ba0, ba1, b2a, b2b, b3a, b3b, b3c, wsh);

    const int B = 16384;
    hipLaunchKernelGGL(vnet_kernel, dim3(B / GB), dim3(NT), LDS_BYTES, stream,
                       x, ba2, wsh, mvg);
    hipLaunchKernelGGL(tail_kernel, dim3(B / TB), dim3(NT), LDS_T_BYTES, stream,
                       mvg, w3d, b3d, wsh, outp);
}

// Round 20
// 113.733 us; speedup vs baseline: 1.7361x; 1.0178x over previous
//
#include <hip/hip_runtime.h>
#include <math.h>

#define NT     512
#define NWAVES 8
#define GB     4
#define NTOK   20
#define NTT_P  5          // token tiles for 80-row phases

typedef _Float16 f16x8 __attribute__((ext_vector_type(8)));
typedef _Float16 f16x4 __attribute__((ext_vector_type(4)));
typedef _Float16 f16x2 __attribute__((ext_vector_type(2)));
typedef float    f32x4 __attribute__((ext_vector_type(4)));

// Raw phase barrier: LDS-visibility only (proven R15/R16).
#define PHASE_BAR() do {                                      \
    asm volatile("s_waitcnt lgkmcnt(0)" ::: "memory");        \
    __builtin_amdgcn_s_barrier();                             \
    asm volatile("" ::: "memory");                            \
    __builtin_amdgcn_sched_barrier(0);                        \
} while (0)

// Wave-local LDS fence (no s_barrier) for same-wave producer->consumer.
#define WAVE_BAR() do {                                       \
    asm volatile("s_waitcnt lgkmcnt(0)" ::: "memory");        \
    asm volatile("" ::: "memory");                            \
    __builtin_amdgcn_sched_barrier(0);                        \
} while (0)

// ---- ws fp16 section: transposed, zero-padded weights W_T[n][kpad] --------
#define WS_W1A  0        // [160][32]   (N=150,K=13)
#define WS_W1B  5120     // [112][160]  (N=100,K=150)
#define WS_WA0  23040    // [112][128]  wa0 rows 0..99
#define WS_WA1  37376    // [112][128]
#define WS_W2A  51712    // [112][128]
#define WS_W2B  66048    // [64][128]   (N=50,K=100)
#define WS_W3A  74240    // [160][64]   (N=150,K=56)
#define WS_W3B  84480    // [112][160]  (N=100,K=150)
#define WS_W3C  102400   // [112][128]  (N=100,K=100)
#define WS_WA0H 116736   // [112][128]  wa0 rows 100..199 (g part)
#define WS_TOTAL 131072
// ---- ws f32 bias section (zero-padded) ------------------------------------
#define WB_BASE 65536
#define WB_B1A  0
#define WB_B1B  160
#define WB_BA0  272
#define WB_BA1  384
#define WB_B2A  496
#define WB_B2B  608
#define WB_B3A  672
#define WB_B3B  832
#define WB_B3C  944
#define WB_WA2  1056
#define WB_N    1168
#define PREP_TOTAL (WS_TOTAL + WB_N)
// ---- mv staging: fp16 [B][64] ---------------------------------------------
#define WS_MV   135168

// ---- main-kernel LDS arena (halves), 52.9 KB -> 3 blocks/CU ---------------
#define LH_A    0
#define LH_B    12160
#define LH_C    23040
#define LH_T1   LH_A          // stride 152
#define LH_S1   LH_A          // stride 136
#define LH_F1   LH_A          // stride 136
#define LH_H1   LH_B          // stride 136
#define LH_FF   LH_B          // [80][72]
#define LH_GQ   LH_C          // [16][136] strip
#define LF_PART 11520         // f32: part [80][8]
#define LF_GB   12672         // f32: gbias [4][112]
#define LF_ATT  13120         // f32: att [80]
#define LF_SS   13200         // f32: ss [24]
#define LDS_DW  13224
#define LDS_BYTES (LDS_DW * 4)

// ---- tail-kernel LDS arena (halves) ---------------------------------------
#define TB      64
#define TL_MV   0        // [64][72]
#define TL_HA   4608     // [64][168]
#define TL_HB   15360    // [64][136]
#define TL_HC   24064    // [64][136]
#define LDS_T_DW   16384
#define LDS_T_BYTES (LDS_T_DW * 4)

// ---------------------------------------------------------------------------
// prep
// ---------------------------------------------------------------------------
__device__ __forceinline__ void prep_one(const float* __restrict__ src, _Float16* dst,
                                         int local, int N, int K, int Ks)
{
    int n = local / Ks, k = local - n * Ks;
    dst[local] = (_Float16)((n < N && k < K) ? src[k * N + n] : 0.f);
}
__device__ __forceinline__ void prep_b(const float* __restrict__ src, float* dst,
                                       int idx, int N)
{
    dst[idx] = (idx < N) ? src[idx] : 0.f;
}

__global__ __launch_bounds__(256)
void prep_kernel(const float* __restrict__ w1a, const float* __restrict__ w1b,
                 const float* __restrict__ wa0, const float* __restrict__ wa1,
                 const float* __restrict__ w2a, const float* __restrict__ w2b,
                 const float* __restrict__ w3a, const float* __restrict__ w3b,
                 const float* __restrict__ w3c, const float* __restrict__ wa2,
                 const float* __restrict__ b1a, const float* __restrict__ b1b,
                 const float* __restrict__ ba0, const float* __restrict__ ba1,
                 const float* __restrict__ b2a, const float* __restrict__ b2b,
                 const float* __restrict__ b3a, const float* __restrict__ b3b,
                 const float* __restrict__ b3c,
                 _Float16* __restrict__ ws)
{
    int g = blockIdx.x * 256 + threadIdx.x;
    if (g >= PREP_TOTAL) return;
    if (g >= WS_TOTAL) {
        float* wb = (float*)ws + WB_BASE;
        int l = g - WS_TOTAL;
        if (l < WB_B1B)      prep_b(b1a, wb + WB_B1A, l - WB_B1A, 150);
        else if (l < WB_BA0) prep_b(b1b, wb + WB_B1B, l - WB_B1B, 100);
        else if (l < WB_BA1) prep_b(ba0, wb + WB_BA0, l - WB_BA0, 100);
        else if (l < WB_B2A) prep_b(ba1, wb + WB_BA1, l - WB_BA1, 100);
        else if (l < WB_B2B) prep_b(b2a, wb + WB_B2A, l - WB_B2A, 100);
        else if (l < WB_B3A) prep_b(b2b, wb + WB_B2B, l - WB_B2B, 50);
        else if (l < WB_B3B) prep_b(b3a, wb + WB_B3A, l - WB_B3A, 150);
        else if (l < WB_B3C) prep_b(b3b, wb + WB_B3B, l - WB_B3B, 100);
        else if (l < WB_WA2) prep_b(b3c, wb + WB_B3C, l - WB_B3C, 100);
        else                 prep_b(wa2, wb + WB_WA2, l - WB_WA2, 100);
        return;
    }
    if (g < WS_W1B)       prep_one(w1a, ws + WS_W1A, g - WS_W1A, 150, 13, 32);
    else if (g < WS_WA0)  prep_one(w1b, ws + WS_W1B, g - WS_W1B, 100, 150, 160);
    else if (g < WS_WA1)  prep_one(wa0, ws + WS_WA0, g - WS_WA0, 100, 100, 128);
    else if (g < WS_W2A)  prep_one(wa1, ws + WS_WA1, g - WS_WA1, 100, 100, 128);
    else if (g < WS_W2B)  prep_one(w2a, ws + WS_W2A, g - WS_W2A, 100, 100, 128);
    else if (g < WS_W3A)  prep_one(w2b, ws + WS_W2B, g - WS_W2B,  50, 100, 128);
    else if (g < WS_W3B)  prep_one(w3a, ws + WS_W3A, g - WS_W3A, 150,  56, 64);
    else if (g < WS_W3C)  prep_one(w3b, ws + WS_W3B, g - WS_W3B, 100, 150, 160);
    else if (g < WS_WA0H) prep_one(w3c, ws + WS_W3C, g - WS_W3C, 100, 100, 128);
    else                  prep_one(wa0 + 100 * 100, ws + WS_WA0H, g - WS_WA0H, 100, 100, 128);
}

// ---------------------------------------------------------------------------
// W-fragment cache (prefetched one phase ahead where proven safe).
// ---------------------------------------------------------------------------
template<int KT, int MTL, int NW>
struct WC {
    static constexpr int IPW = (MTL + NW - 1) / NW;
    f16x8 wf[IPW][KT];
    f32x4 bv[IPW];
};

template<int KT, int MTL, int NW, bool LOADB>
__device__ __forceinline__ void load_w(WC<KT, MTL, NW>& W,
                                       const _Float16* __restrict__ WT, const int Bs,
                                       const float* __restrict__ biasp,
                                       const int wv, const int lane)
{
    const int cl = lane & 15, kq = lane >> 4;
#pragma unroll
    for (int ii = 0; ii < WC<KT, MTL, NW>::IPW; ++ii) {
        const int mt = wv + ii * NW;
        if (mt < MTL) {
            const _Float16* Wp = WT + (mt * 16 + cl) * Bs + kq * 8;
#pragma unroll
            for (int kt = 0; kt < KT; ++kt) W.wf[ii][kt] = *(const f16x8*)(Wp + kt * 32);
            if (LOADB) W.bv[ii] = *(const f32x4*)(biasp + mt * 16 + kq * 4);
        }
    }
}

// ---------------------------------------------------------------------------
// Compute part of the swapped-operand GEMM with preloaded W (R14/R16-proven).
// T5: MFMA cluster wrapped in s_setprio(1)/(0) — with 3 blocks/CU at
// different phases, the CU scheduler can favor the MFMA-issuing wave over
// co-resident waves doing W-loads/ds_reads.
// OMODE 0: fp16 Y[token][feat] b64 store, clamped fb<CLW.
// OMODE 1: f32x4 -> gbias[token][feat] (token<GB).
// OMODE 2: scores-partial via kq-reduce shfl_xor(16/32).
// BMODE 0: bias from preloaded bv. 1: gbias[token/20][feat..].
// ---------------------------------------------------------------------------
template<int KT, int MTL, int NTT, bool RELU, int BMODE, int OMODE, int CLW, int NW>
__device__ __forceinline__ void gemm_c(const WC<KT, MTL, NW>& W,
                                       const _Float16* X, const int Xs,
                                       const float* gbias,
                                       _Float16* Y, const int Ys,
                                       float* part, const float* __restrict__ wa2p,
                                       const int wv, const int lane)
{
    const int cl = lane & 15, kq = lane >> 4;
#pragma unroll
    for (int ii = 0; ii < WC<KT, MTL, NW>::IPW; ++ii) {
        const int mt = wv + ii * NW;
        if (mt >= MTL) break;
        const int fb = mt * 16 + kq * 4;
#pragma unroll
        for (int nt = 0; nt < NTT; ++nt) {
            const _Float16* Xp = X + (nt * 16 + cl) * Xs + kq * 8;
            f16x8 xf[KT];
#pragma unroll
            for (int kt = 0; kt < KT; ++kt) xf[kt] = *(const f16x8*)(Xp + kt * 32);
            f32x4 acc = {0.f, 0.f, 0.f, 0.f};
            __builtin_amdgcn_s_setprio(1);
#pragma unroll
            for (int kt = 0; kt < KT; ++kt)
                acc = __builtin_amdgcn_mfma_f32_16x16x32_f16(W.wf[ii][kt], xf[kt], acc, 0, 0, 0);
            __builtin_amdgcn_s_setprio(0);
            const int token = nt * 16 + cl;
            if (OMODE == 1) {
                if (cl < GB) {
                    f32x4 o = acc + W.bv[ii];
                    *(f32x4*)((float*)Y + cl * 112 + fb) = o;
                }
            } else if (OMODE == 2) {
                f32x4 y = acc + W.bv[ii];
                y[0] = fmaxf(y[0], 0.f); y[1] = fmaxf(y[1], 0.f);
                y[2] = fmaxf(y[2], 0.f); y[3] = fmaxf(y[3], 0.f);
                f32x4 w4 = *(const f32x4*)(wa2p + fb);
                float p = y[0] * w4[0] + y[1] * w4[1] + y[2] * w4[2] + y[3] * w4[3];
                p += __shfl_xor(p, 16);
                p += __shfl_xor(p, 32);
                if (kq == 0) part[token * 8 + mt] = p;
            } else {
                f32x4 bb;
                if (BMODE == 1)
                    bb = *(const f32x4*)(gbias + (token / NTOK) * 112 + fb);
                else
                    bb = W.bv[ii];
                f32x4 y = acc + bb;
                if (RELU) {
                    y[0] = fmaxf(y[0], 0.f); y[1] = fmaxf(y[1], 0.f);
                    y[2] = fmaxf(y[2], 0.f); y[3] = fmaxf(y[3], 0.f);
                }
                if (fb < CLW) {
                    f16x4 o = { (_Float16)y[0], (_Float16)y[1],
                                (_Float16)y[2], (_Float16)y[3] };
                    *(f16x4*)(Y + token * Ys + fb) = o;
                }
            }
        }
    }
}

// ---------------------------------------------------------------------------
// Monolithic swapped-operand GEMM (R12-proven): W loaded in-phase.
// ---------------------------------------------------------------------------
template<int KT, int MTL, int NTT, bool RELU, int BMODE, int OMODE, int CLW, int NW>
__device__ __forceinline__ void gemm_sw(const _Float16* X, const int Xs,
                                        const _Float16* __restrict__ WT, const int Bs,
                                        const float* __restrict__ biasp,
                                        const float* gbias,
                                        _Float16* Y, const int Ys,
                                        float* part, const float* __restrict__ wa2p,
                                        const int wv, const int lane)
{
    WC<KT, MTL, NW> W;
    load_w<KT, MTL, NW, true>(W, WT, Bs, biasp ? biasp : (const float*)WT, wv, lane);
    gemm_c<KT, MTL, NTT, RELU, BMODE, OMODE, CLW, NW>(W, X, Xs, gbias, Y, Ys,
                                                      part, wa2p, wv, lane);
}

// ===========================================================================
// MAIN kernel: 9 phases; Mg folded into M1; T5 setprio on MFMA clusters.
// ===========================================================================
__global__ __launch_bounds__(NT, 6)
void vnet_kernel(const float* __restrict__ x,
                 const float* __restrict__ ba2,
                 const _Float16* __restrict__ wsh,
                 _Float16* __restrict__ mvg)
{
    extern __shared__ float lds_f[];
    _Float16* lds_h = (_Float16*)lds_f;

    const int tid  = threadIdx.x;
    const int lane = tid & 63, wv = tid >> 6;
    const int b0   = blockIdx.x * GB;
    const float* wb = (const float*)wsh + WB_BASE;

    _Float16* xa  = lds_h + LH_C;
    _Float16* gqh = lds_h + LH_GQ;
    _Float16* h1w = lds_h + LH_H1;
    float* gbias = lds_f + LF_GB;
    float* att   = lds_f + LF_ATT;
    float* ss    = lds_f + LF_SS;
    float* part  = lds_f + LF_PART;

    WC<1, 10, 8> Wp2;   // w1a
    WC<5, 7, 8>  Wp3;   // w1b
    WC<4, 7, 8>  Wg;    // wa0_hi (gbias MFMA)
    WC<4, 7, 8>  Wm1;   // wa0_lo (bias via gbias)

    // ---- P1: prefetch W(P2); x -> C [token][40]; targeted pad zeroing ----
    load_w<1, 10, 8, true>(Wp2, wsh + WS_W1A, 32, wb + WB_B1A, wv, lane);
    const float* xg = x + (size_t)b0 * (NTOK * 13);
    for (int t = tid; t < GB * NTOK * 13; t += NT) {
        int row = t / 13, d = t - row * 13;
        xa[row * 40 + d] = (_Float16)xg[t];
    }
    for (int t = tid; t < 80 * 27; t += NT) {
        int row = t / 27, c = 13 + (t - row * 27);
        xa[row * 40 + c] = (_Float16)0.f;
    }
    for (int t = tid; t < 80 * 24; t += NT) {
        int row = t / 24, c = 112 + (t - row * 24);
        h1w[row * 136 + c] = (_Float16)0.f;
    }
    if (tid < 8) h1w[tid] = (_Float16)0.f;
    if (tid < GB * 6) {
        int b = tid / 6, d = tid - b * 6;
        ss[tid] = xg[b * (NTOK * 13) + d];   // x[b,0,d]
    }
    PHASE_BAR();

    // ---- P2: t1 = relu(x @ w1a + b1a) -> A [80][152]; prefetch w1b -------
    load_w<5, 7, 8, true>(Wp3, wsh + WS_W1B, 160, wb + WB_B1B, wv, lane);
    gemm_c<1, 10, NTT_P, true, 0, 0, 152, 8>(Wp2, xa, 40, nullptr,
        lds_h + LH_T1, 152, nullptr, nullptr, wv, lane);
    PHASE_BAR();

    // ---- P3: h1 = relu(t1 @ w1b + b1b) -> B [80][136] --------------------
    gemm_c<5, 7, NTT_P, true, 0, 0, 10000, 8>(Wp3, lds_h + LH_T1, 152, nullptr,
        h1w, 136, nullptr, nullptr, wv, lane);
    PHASE_BAR();

    // ---- P4: gq strip; prefetch Wg = wa0_hi and Wm1 = wa0_lo -------------
    load_w<4, 7, 8, true>(Wg, wsh + WS_WA0H, 128, wb + WB_BA0, wv, lane);
    load_w<4, 7, 8, false>(Wm1, wsh + WS_WA0, 128, nullptr, wv, lane);
    const _Float16* h1 = h1w;
    const uint* h1u = (const uint*)h1;
    for (int t = tid; t < GB * 50; t += NT) {
        int b = t / 50, cp = t - b * 50;
        float s0 = 0.f, s1 = 0.f;
#pragma unroll
        for (int n = 0; n < NTOK; ++n) {
            uint v = h1u[(b * NTOK + n) * 68 + cp];
            f16x2 pq = *(const f16x2*)&v;
            s0 += (float)pq.x; s1 += (float)pq.y;
        }
        f16x2 g = { (_Float16)(s0 * 0.05f), (_Float16)(s1 * 0.05f) };
        *(f16x2*)(gqh + b * 136 + 2 * cp) = g;
    }
    PHASE_BAR();

    // ---- M1': fused gbias + s1 (wave-local dep; proven R19) --------------
    gemm_c<4, 7, 1, false, 0, 1, 10000, 8>(Wg, gqh, 136, nullptr,
        (_Float16*)gbias, 0, nullptr, nullptr, wv, lane);
    WAVE_BAR();
    gemm_c<4, 7, NTT_P, true, 1, 0, 10000, 8>(Wm1, h1, 136, gbias,
        lds_h + LH_S1, 136, nullptr, nullptr, wv, lane);
    PHASE_BAR();

    // ---- M2: s2-scores partials from s1 (no s2 store) -> part ------------
    gemm_sw<4, 7, NTT_P, true, 0, 2, 10000, 8>(lds_h + LH_S1, 136, wsh + WS_WA1,
        128, wb + WB_BA1, nullptr, nullptr, 0, part, wb + WB_WA2, wv, lane);
    PHASE_BAR();

    // ---- M3: f1 = relu(h1 @ w2a + b2a) -> A (s1 dead) --------------------
    gemm_sw<4, 7, NTT_P, true, 0, 0, 10000, 8>(h1, 136, wsh + WS_W2A, 128,
        wb + WB_B2A, nullptr, lds_h + LH_F1, 136, nullptr, nullptr, wv, lane);
    PHASE_BAR();

    // ---- M4: f = f1 @ w2b + b2b -> B head (waves 0-3); softmax (4-7) -----
    if (wv < 4) {
        gemm_sw<4, 4, NTT_P, false, 0, 0, 10000, 4>(lds_h + LH_F1, 136,
            wsh + WS_W2B, 128, wb + WB_B2B, nullptr, lds_h + LH_FF, 72,
            nullptr, nullptr, wv, lane);
    } else {
        const int b = wv - 4;
        float sc = -1e30f;
        if (lane < NTOK) {
            sc = ba2[0];
            const float* pr = part + (b * NTOK + lane) * 8;
#pragma unroll
            for (int m = 0; m < 7; ++m) sc += pr[m];
        }
        float mx = sc;
#pragma unroll
        for (int off = 16; off; off >>= 1) mx = fmaxf(mx, __shfl_xor(mx, off, 32));
        float e = (lane < NTOK) ? expf(sc - mx) : 0.f;
        float s = e;
#pragma unroll
        for (int off = 16; off; off >>= 1) s += __shfl_xor(s, off, 32);
        if (lane < NTOK) att[b * NTOK + lane] = e / s;
    }
    PHASE_BAR();

    // ---- P10: mv[b][c] = [ss | wf | 0-pad] -> GLOBAL fp16 [B][64] --------
    const _Float16* fh = lds_h + LH_FF;
    for (int t = tid; t < GB * 64; t += NT) {
        int b = t >> 6, c = t & 63;
        float v = 0.f;
        if (c < 6) {
            v = ss[b * 6 + c];
        } else if (c < 56) {
            const int cc = c - 6;
            const float* ab = att + b * NTOK;
            float acc = 0.f;
#pragma unroll
            for (int n = 0; n < NTOK; ++n)
                acc = fmaf((float)fh[(b * NTOK + n) * 72 + cc], ab[n], acc);
            v = acc;
        }
        mvg[(size_t)(b0 + b) * 64 + c] = (_Float16)v;
    }
}

// ===========================================================================
// TAIL kernel (R16 structure + T5 setprio).
// ===========================================================================
template<int KT, int MTL, int NTT, bool RELU, int NW>
__device__ __forceinline__ void gemm_wc(const WC<KT, MTL, NW>& W,
                                        const _Float16* X, const int Xs,
                                        _Float16* Y, const int Ys,
                                        const int wv, const int lane)
{
    const int cl = lane & 15, kq = lane >> 4;
#pragma unroll
    for (int ii = 0; ii < WC<KT, MTL, NW>::IPW; ++ii) {
        const int mt = wv + ii * NW;
        if (mt >= MTL) break;
        const int fb = mt * 16 + kq * 4;
#pragma unroll
        for (int nt = 0; nt < NTT; ++nt) {
            const _Float16* Xp = X + (nt * 16 + cl) * Xs + kq * 8;
            f16x8 xf[KT];
#pragma unroll
            for (int kt = 0; kt < KT; ++kt) xf[kt] = *(const f16x8*)(Xp + kt * 32);
            f32x4 acc = {0.f, 0.f, 0.f, 0.f};
            __builtin_amdgcn_s_setprio(1);
#pragma unroll
            for (int kt = 0; kt < KT; ++kt)
                acc = __builtin_amdgcn_mfma_f32_16x16x32_f16(W.wf[ii][kt], xf[kt], acc, 0, 0, 0);
            __builtin_amdgcn_s_setprio(0);
            const int token = nt * 16 + cl;
            f32x4 y = acc + W.bv[ii];
            if (RELU) {
                y[0] = fmaxf(y[0], 0.f); y[1] = fmaxf(y[1], 0.f);
                y[2] = fmaxf(y[2], 0.f); y[3] = fmaxf(y[3], 0.f);
            }
            f16x4 o = { (_Float16)y[0], (_Float16)y[1],
                        (_Float16)y[2], (_Float16)y[3] };
            *(f16x4*)(Y + token * Ys + fb) = o;
        }
    }
}

__global__ __launch_bounds__(NT)
void tail_kernel(const _Float16* __restrict__ mvg,
                 const float* __restrict__ w3d, const float* __restrict__ b3d,
                 const _Float16* __restrict__ wsh,
                 float* __restrict__ outp)
{
    extern __shared__ float lds_f[];
    _Float16* lds_h = (_Float16*)lds_f;

    const int tid  = threadIdx.x;
    const int lane = tid & 63, wv = tid >> 6;
    const int g0   = blockIdx.x * TB;
    const float* wb = (const float*)wsh + WB_BASE;

    WC<2, 10, 8> Wt1; WC<5, 7, 8> Wt2; WC<4, 7, 8> Wt3;
    load_w<2, 10, 8, true>(Wt1, wsh + WS_W3A, 64, wb + WB_B3A, wv, lane);

    // ---- L: load mv -> LDS stride 72 -------------------------------------
    _Float16* mvT = lds_h + TL_MV;
    {
        const uint* src = (const uint*)(mvg + (size_t)g0 * 64);
        uint* dst = (uint*)mvT;
        for (int t = tid; t < TB * 32; t += NT) {
            int row = t >> 5, c = t & 31;
            dst[row * 36 + c] = src[t];
        }
    }
    for (int t = tid; t < (TL_HC - TL_HB) / 2; t += NT)
        ((uint*)(lds_h + TL_HB))[t] = 0u;
    __syncthreads();

    // ---- T1: ha = relu(mv @ w3a + b3a)  [64][168], K=64 ------------------
    load_w<5, 7, 8, true>(Wt2, wsh + WS_W3B, 160, wb + WB_B3B, wv, lane);
    gemm_wc<2, 10, 4, true, 8>(Wt1, mvT, 72, lds_h + TL_HA, 168, wv, lane);
    __syncthreads();

    // ---- T2: hb = relu(ha @ w3b + b3b)  [64][136], K=160 -----------------
    load_w<4, 7, 8, true>(Wt3, wsh + WS_W3C, 128, wb + WB_B3C, wv, lane);
    gemm_wc<5, 7, 4, true, 8>(Wt2, lds_h + TL_HA, 168, lds_h + TL_HB, 136, wv, lane);
    __syncthreads();

    // ---- T3: hc = relu(hb @ w3c + b3c)  [64][136], K=128 -----------------
    gemm_wc<4, 7, 4, true, 8>(Wt3, lds_h + TL_HB, 136, lds_h + TL_HC, 136, wv, lane);
    __syncthreads();

    // ---- T4: out = hc . w3d + b3d  (8 lanes per batch) -------------------
    {
        const int b = tid >> 3, kl = tid & 7;
        const _Float16* hc = lds_h + TL_HC + b * 136;
        float acc = 0.f;
#pragma unroll 13
        for (int k = kl; k < 100; k += 8)
            acc = fmaf((float)hc[k], w3d[k], acc);
        acc += __shfl_xor(acc, 1);
        acc += __shfl_xor(acc, 2);
        acc += __shfl_xor(acc, 4);
        if (kl == 0) outp[g0 + b] = acc + b3d[0];
    }
}

extern "C" void kernel_launch(void* const* d_in, const int* in_sizes, int n_in,
                              void* d_out, int out_size, void* d_ws, size_t ws_size,
                              hipStream_t stream)
{
    const float* x   = (const float*)d_in[0];
    const float* w1a = (const float*)d_in[1];
    const float* b1a = (const float*)d_in[2];
    const float* w1b = (const float*)d_in[3];
    const float* b1b = (const float*)d_in[4];
    const float* wa0 = (const float*)d_in[5];
    const float* ba0 = (const float*)d_in[6];
    const float* wa1 = (const float*)d_in[7];
    const float* ba1 = (const float*)d_in[8];
    const float* wa2 = (const float*)d_in[9];
    const float* ba2 = (const float*)d_in[10];
    const float* w2a = (const float*)d_in[11];
    const float* b2a = (const float*)d_in[12];
    const float* w2b = (const float*)d_in[13];
    const float* b2b = (const float*)d_in[14];
    const float* w3a = (const float*)d_in[15];
    const float* b3a = (const float*)d_in[16];
    const float* w3b = (const float*)d_in[17];
    const float* b3b = (const float*)d_in[18];
    const float* w3c = (const float*)d_in[19];
    const float* b3c = (const float*)d_in[20];
    const float* w3d = (const float*)d_in[21];
    const float* b3d = (const float*)d_in[22];
    float* outp = (float*)d_out;
    _Float16* wsh = (_Float16*)d_ws;
    _Float16* mvg = wsh + WS_MV;

    hipFuncSetAttribute((const void*)vnet_kernel,
                        hipFuncAttributeMaxDynamicSharedMemorySize, LDS_BYTES);
    hipFuncSetAttribute((const void*)tail_kernel,
                        hipFuncAttributeMaxDynamicSharedMemorySize, LDS_T_BYTES);

    hipLaunchKernelGGL(prep_kernel, dim3((PREP_TOTAL + 255) / 256), dim3(256),
                       0, stream,
                       w1a, w1b, wa0, wa1, w2a, w2b, w3a, w3b, w3c, wa2,
                       b1a, b1b, ba0, ba1, b2a, b2b, b3a, b3b, b3c, wsh);

    const int B = 16384;
    hipLaunchKernelGGL(vnet_kernel, dim3(B / GB), dim3(NT), LDS_BYTES, stream,
                       x, ba2, wsh, mvg);
    hipLaunchKernelGGL(tail_kernel, dim3(B / TB), dim3(NT), LDS_T_BYTES, stream,
                       mvg, w3d, b3d, wsh, outp);
}